// Round 4
// baseline (419.581 us; speedup 1.0000x reference)
//
#include <hip/hip_runtime.h>

// Problem constants (from reference setup_inputs)
#define BB 2
#define NN 4096
#define DD 512
#define EE 16
#define HH 2048
#define CAP 1024            // capacity = int((4096*2)*2.0/16) = 1024
#define NTOK (BB*NN)        // 8192
#define MM (BB*CAP)         // 2048 = per-expert logical M
#define MAXSTRIP 96         // 256-row strips: sum ceil(used/256) <= 64+32 = 96

typedef unsigned short ushort_t;
typedef __attribute__((ext_vector_type(8))) short bf16x8;   // 8 bf16 = 4 VGPRs
typedef __attribute__((ext_vector_type(4))) float floatx4;  // MFMA accumulator

// round-to-nearest-even f32 -> bf16 bit pattern
__device__ __forceinline__ ushort_t f2bf(float f) {
    union { float f; unsigned u; } v; v.f = f;
    unsigned r = v.u + 0x7fffu + ((v.u >> 16) & 1u);
    return (ushort_t)(r >> 16);
}

// async global->LDS, 16B per lane (global_load_lds_dwordx4).
__device__ __forceinline__ void cp16(const void* g, void* l) {
    __builtin_amdgcn_global_load_lds(
        (const __attribute__((address_space(1))) void*)g,
        (__attribute__((address_space(3))) void*)l, 16, 0, 0);
}

// ---------------------------------------------------------------------------
// Kernel 1: gating (f32-exact selection) + fused bf16 conversion of x.
// ---------------------------------------------------------------------------
__launch_bounds__(256)
__global__ void gating_kernel(const float* __restrict__ x,
                              const float* __restrict__ wg,
                              int* __restrict__ e1, int* __restrict__ e2,
                              float* __restrict__ g1, float* __restrict__ g2,
                              ushort_t* __restrict__ xbf) {
    int wave = threadIdx.x >> 6;
    int lane = threadIdx.x & 63;
    int t = blockIdx.x * 4 + wave;
    const float* xp = x + (size_t)t * DD;

    float4 xa = ((const float4*)xp)[lane * 2];
    float4 xb = ((const float4*)xp)[lane * 2 + 1];
    float xs[8] = {xa.x, xa.y, xa.z, xa.w, xb.x, xb.y, xb.z, xb.w};

    ushort4 h0, h1;
    h0.x = f2bf(xs[0]); h0.y = f2bf(xs[1]); h0.z = f2bf(xs[2]); h0.w = f2bf(xs[3]);
    h1.x = f2bf(xs[4]); h1.y = f2bf(xs[5]); h1.z = f2bf(xs[6]); h1.w = f2bf(xs[7]);
    ushort4* xo = (ushort4*)(xbf + (size_t)t * DD);
    xo[lane * 2] = h0; xo[lane * 2 + 1] = h1;

    float acc[EE];
#pragma unroll
    for (int e = 0; e < EE; e++) acc[e] = 0.f;
    int d0 = lane * 8;
#pragma unroll
    for (int j = 0; j < 8; j++) {
        const float* wrow = wg + (d0 + j) * EE;
#pragma unroll
        for (int e = 0; e < EE; e++) acc[e] = fmaf(xs[j], wrow[e], acc[e]);
    }
#pragma unroll
    for (int off = 32; off > 0; off >>= 1) {
#pragma unroll
        for (int e = 0; e < EE; e++) acc[e] += __shfl_xor(acc[e], off, 64);
    }
    if (lane == 0) {
        float m = acc[0];
#pragma unroll
        for (int e = 1; e < EE; e++) m = fmaxf(m, acc[e]);
        float p[EE]; float s = 0.f;
#pragma unroll
        for (int e = 0; e < EE; e++) { p[e] = __expf(acc[e] - m); s += p[e]; }
        float inv = 1.f / s;
#pragma unroll
        for (int e = 0; e < EE; e++) p[e] *= inv;
        int i1 = 0; float v1 = p[0];
#pragma unroll
        for (int e = 1; e < EE; e++) if (p[e] > v1) { v1 = p[e]; i1 = e; }
        int i2 = (i1 == 0) ? 1 : 0; float v2 = p[i2];
#pragma unroll
        for (int e = 0; e < EE; e++)
            if (e != i1 && p[e] > v2) { v2 = p[e]; i2 = e; }
        float denom = v1 + v2 + 1e-9f;
        e1[t] = i1; e2[t] = i2;
        g1[t] = v1 / denom; g2[t] = v2 / denom;
    }
}

// ---------------------------------------------------------------------------
// Kernel 2: per-(b,e) exclusive scan -> slot assignment with capacity drop.
// Writes s2t (token or -1 for ALL CAP slots), s2g, used[e][b].
// ---------------------------------------------------------------------------
__launch_bounds__(256)
__global__ void scan_kernel(const int* __restrict__ e1, const int* __restrict__ e2,
                            const float* __restrict__ g1, const float* __restrict__ g2,
                            int* __restrict__ s2t, float* __restrict__ s2g,
                            int* __restrict__ used) {
    int b = blockIdx.x / EE;
    int e = blockIdx.x % EE;
    int tid = threadIdx.x;
    const int base = b * NN;
    int n0 = tid * 16;

    unsigned m1 = 0, m2 = 0;
    int c1 = 0, c2 = 0;
#pragma unroll
    for (int j = 0; j < 16; j++) {
        int n = n0 + j;
        if (e1[base + n] == e) { m1 |= 1u << j; c1++; }
        if (e2[base + n] == e) { m2 |= 1u << j; c2++; }
    }
    __shared__ int s1[256], s2[256];
    __shared__ int s_used;
    s1[tid] = c1; s2[tid] = c2;
    __syncthreads();
    for (int off = 1; off < 256; off <<= 1) {
        int a1 = (tid >= off) ? s1[tid - off] : 0;
        int a2 = (tid >= off) ? s2[tid - off] : 0;
        __syncthreads();
        s1[tid] += a1; s2[tid] += a2;
        __syncthreads();
    }
    int total1 = s1[255];
    int total2 = s2[255];
    int kept1 = min(total1, CAP);
    int ex1 = s1[tid] - c1;
    int ex2 = s2[tid] - c2 + kept1;
    const int sbase = (e * BB + b) * CAP;
#pragma unroll
    for (int j = 0; j < 16; j++) {
        int n = n0 + j;
        if (m1 & (1u << j)) {
            if (ex1 < CAP) { s2t[sbase + ex1] = base + n; s2g[sbase + ex1] = g1[base + n]; }
            ex1++;
        }
        if (m2 & (1u << j)) {
            if (ex2 < CAP) { s2t[sbase + ex2] = base + n; s2g[sbase + ex2] = g2[base + n]; }
            ex2++;
        }
    }
    if (tid == 255) {
        int kept2 = min(total2, max(0, CAP - kept1));
        int u = kept1 + kept2;
        used[e * BB + b] = u;
        s_used = u;
    }
    __syncthreads();
    for (int i = s_used + tid; i < CAP; i += 256) s2t[sbase + i] = -1;
}

// ---------------------------------------------------------------------------
// Kernel 3: build XCD-pinned job schedules over 256-row strips.
// meta layout (ints): [0..7] count1/xcd, [8..15] count2/xcd,
//                     [16..4111] sched1 (8 x 512), [4112..5135] sched2 (8 x 128)
// job = (e<<17) | (wi<<9) | (ytile<<5) | c
//   GEMM1: c in [0,8)  -> col0 = c*256
//   GEMM2: c in [0,4)  -> col0 = (c>>1)*256, ksplit = c&1 (K halves of 1024)
// ---------------------------------------------------------------------------
__global__ void schedule_kernel(const int* __restrict__ used, int* __restrict__ meta) {
    __shared__ int ns[32], pre[32];
    int i = threadIdx.x;
    if (i < 32) {
        int e = i >> 1, b = i & 1;
        ns[i] = (used[e * BB + b] + 255) >> 8;
    }
    __syncthreads();
    if (i == 0) {
        int acc = 0;
        for (int j = 0; j < 32; j++) { pre[j] = acc; acc += ns[j]; }
    }
    __syncthreads();
    if (i < 16) {
        int e = i;
        int xcd = e & 7;
        int mine  = ns[2 * e] + ns[2 * e + 1];
        int po    = (e < 8) ? (e + 8) : (e - 8);
        int other = ns[2 * po] + ns[2 * po + 1];
        if (e < 8) {
            meta[xcd]     = (mine + other) * 8;    // GEMM1 jobs on this XCD
            meta[8 + xcd] = (mine + other) * 4;    // GEMM2 jobs on this XCD
        }
        int off = (e < 8) ? 0 : other;             // partner's jobs come first
        int* sc1 = meta + 16 + xcd * 512 + off * 8;
        int j = 0;
        for (int col = 0; col < 8; col++)
            for (int bb = 0; bb < 2; bb++)
                for (int s = 0; s < ns[2 * e + bb]; s++) {
                    int wi = pre[2 * e + bb] + s;
                    sc1[j++] = (e << 17) | (wi << 9) | ((bb * 4 + s) << 5) | col;
                }
        int* sc2 = meta + 16 + 4096 + xcd * 128 + off * 4;
        j = 0;
        for (int c = 0; c < 4; c++)
            for (int bb = 0; bb < 2; bb++)
                for (int s = 0; s < ns[2 * e + bb]; s++) {
                    int wi = pre[2 * e + bb] + s;
                    sc2[j++] = (e << 17) | (wi << 9) | ((bb * 4 + s) << 5) | c;
                }
    }
}

// ---------------------------------------------------------------------------
// Kernel 4: per-expert transpose + bf16: in f32 [E][R][C] -> out bf16 [E][C][R].
// ---------------------------------------------------------------------------
__global__ void transpose_bf16(const float* __restrict__ in,
                               ushort_t* __restrict__ outp, int R, int C) {
    __shared__ float tile[32][33];
    const float* slab = in + (size_t)blockIdx.z * R * C;
    ushort_t* oslab = outp + (size_t)blockIdx.z * R * C;
    int c0 = blockIdx.x * 32, r0 = blockIdx.y * 32;
    int tx = threadIdx.x, ty = threadIdx.y;   // (32, 8)
#pragma unroll
    for (int j = 0; j < 4; j++)
        tile[ty + j * 8][tx] = slab[(size_t)(r0 + ty + j * 8) * C + c0 + tx];
    __syncthreads();
#pragma unroll
    for (int j = 0; j < 4; j++)
        oslab[(size_t)(c0 + ty + j * 8) * R + r0 + tx] = f2bf(tile[tx][ty + j * 8]);
}

// ---------------------------------------------------------------------------
// Kernel 5: bf16 MFMA GEMM, 256x256 tile, BK=64, 512 threads (8 waves 2Mx4N),
// 8-PHASE counted-vmcnt schedule (T3+T4) + s_setprio around MFMA (T5).
//
// LDS: per buffer (2), A and B each split into 2 quadrant-halves of 16KB:
//   A-half h = global rows {h*64..h*64+63} u {128+h*64..+63}  (M-stripe parity)
//   B-half h = global rows {wn+h*32..+31 : wn in 0,64,128,192} (N-stripe parity)
// Phase p (p=0..3 per K-tile) computes quadrant (qm,qn)=(p>>1,p&1), reading
// exactly A-half qm and B-half qn. Each phase ends with lgkmcnt(0)+s_barrier,
// which FREES the regions last read in that phase; each phase stages exactly
// one half (2 global_load_lds) into a region freed earlier, 2 K-tiles ahead:
//   P1:V.A1[T+1] P2:V.B1[T+1] P3:U.A0[T+2] P4:U.B0[T+2]
//   P5:U.A1[T+2] P6:U.B1[T+2] P7:V.A0[T+3] P8:V.B0[T+3]
// Counted waits (ledger-verified): vmcnt(8) at P4/P8-close, vmcnt(6) at
// P1/P5-close; never 0 in steady state. Last iteration peeled (drain 6,4,0).
//   MODE 0 (GEMM1): K=512 (8 K-tiles), A gathered from xbf via s2t -> relu ->
//                   hid[strip].
//   MODE 1 (GEMM2): K=1024 per job (split-K 2, 16 K-tiles), A = hid[strip],
//                   epilogue gate*acc atomicAdd -> out.
// ---------------------------------------------------------------------------
template <int MODE>
__launch_bounds__(512)
__global__ void gemm_mfma(const ushort_t* __restrict__ Abase,
                          const ushort_t* __restrict__ Bt,
                          void* __restrict__ Cout,
                          const int* __restrict__ meta,
                          const int* __restrict__ s2t,
                          const float* __restrict__ s2g) {
    constexpr int BROW = (MODE == 0) ? DD : HH;   // B^T row length (full K)
    constexpr int KJOB = (MODE == 0) ? DD : (HH / 2);
    constexpr int KT = KJOB / 64;                 // K-tiles: 8 or 16 (even)
    constexpr int NITER = KT / 2;                 // 4 or 8

    int xcd = blockIdx.x;
    if ((int)blockIdx.y >= meta[(MODE == 0 ? 0 : 8) + xcd]) return;
    int job = meta[16 + (MODE == 0 ? 0 : 4096) + xcd * (MODE == 0 ? 512 : 128) + blockIdx.y];
    int c     = job & 31;
    int ytile = (job >> 5) & 15;
    int wi    = (job >> 9) & 255;
    int e     = job >> 17;
    int col0  = (MODE == 0) ? c * 256 : (c >> 1) * 256;
    int koff  = (MODE == 0) ? 0 : (c & 1) * (HH / 2);

    // [buf][half][128*64] each 16KB; total 128KB
    __shared__ ushort_t As[2][2][128 * 64];
    __shared__ ushort_t Bs[2][2][128 * 64];

    int tid = threadIdx.x;
    int lane = tid & 63;
    int wid = tid >> 6;
    int wave_m = (wid & 1) * 128;     // 2 waves along M
    int wave_n = (wid >> 1) * 64;     // 4 waves along N
    int lm = lane & 15;
    int quad = lane >> 4;

    // Staging pointers: half h, iteration it: chunk p = it*512+tid,
    // local row r = p>>3, 16B col cg = (p&7)^(r&7) (inverse swizzle).
    const ushort_t* gA[2][2];
    const ushort_t* gB[2][2];
#pragma unroll
    for (int h = 0; h < 2; h++) {
#pragma unroll
        for (int it = 0; it < 2; it++) {
            int p = it * 512 + tid;
            int r = p >> 3;
            int cg = (p & 7) ^ (r & 7);
            int gra = h * 64 + (r & 63) + ((r >> 6) << 7);      // A global row
            int grb = h * 32 + (r & 31) + ((r >> 5) << 6);      // B global row
            if (MODE == 0) {
                int tok = s2t[e * MM + ytile * 256 + gra];
                if (tok < 0) tok = 0;   // dummy valid row; masked downstream
                gA[h][it] = Abase + (size_t)tok * DD + cg * 8;
            } else {
                gA[h][it] = Abase + (size_t)(wi * 256 + gra) * HH + koff + cg * 8;
            }
            gB[h][it] = Bt + (size_t)e * HH * DD + (size_t)(col0 + grb) * BROW
                        + (MODE == 0 ? 0 : koff) + cg * 8;
        }
    }

#define STAGEA(BUF, H, KTI)                                            \
    do {                                                               \
        cp16(gA[H][0] + (KTI) * 64, &As[BUF][H][(size_t)tid * 8]);     \
        cp16(gA[H][1] + (KTI) * 64, &As[BUF][H][(size_t)(512 + tid) * 8]); \
    } while (0)
#define STAGEB(BUF, H, KTI)                                            \
    do {                                                               \
        cp16(gB[H][0] + (KTI) * 64, &Bs[BUF][H][(size_t)tid * 8]);     \
        cp16(gB[H][1] + (KTI) * 64, &Bs[BUF][H][(size_t)(512 + tid) * 8]); \
    } while (0)

    floatx4 acc[8][4];
#pragma unroll
    for (int i = 0; i < 8; i++)
#pragma unroll
        for (int j = 0; j < 4; j++)
            acc[i][j] = (floatx4)(0.f);

    int arow = (wave_m >> 1) + lm;    // A-chunk local row base (+ m*16)
    int brow = (wave_n >> 1) + lm;    // B-chunk local row base (+ n*16)
    int sw0 = (quad ^ (lm & 7)) * 8;          // ks=0 16B-chunk (swizzled)
    int sw1 = ((4 + quad) ^ (lm & 7)) * 8;    // ks=1

    // One phase: quadrant (QM,QN) of buffer BF; STAGES = one half; CLOSE =
    // closing waitcnt+barrier (frees this phase's last-read regions, and
    // carries the counted vmcnt needed by the NEXT phase's ds_reads).
#define PHASE(BF, QM, QN, STAGES, CLOSE)                                      \
    do {                                                                      \
        bf16x8 a0[4], a1[4], b0[2], b1[2];                                    \
        _Pragma("unroll")                                                     \
        for (int m = 0; m < 4; m++) {                                         \
            a0[m] = *(const bf16x8*)&As[BF][QM][(arow + m * 16) * 64 + sw0];  \
            a1[m] = *(const bf16x8*)&As[BF][QM][(arow + m * 16) * 64 + sw1];  \
        }                                                                     \
        _Pragma("unroll")                                                     \
        for (int n = 0; n < 2; n++) {                                         \
            b0[n] = *(const bf16x8*)&Bs[BF][QN][(brow + n * 16) * 64 + sw0];  \
            b1[n] = *(const bf16x8*)&Bs[BF][QN][(brow + n * 16) * 64 + sw1];  \
        }                                                                     \
        STAGES;                                                               \
        asm volatile("s_barrier" ::: "memory");                               \
        __builtin_amdgcn_s_setprio(1);                                        \
        _Pragma("unroll")                                                     \
        for (int m = 0; m < 4; m++)                                           \
            _Pragma("unroll")                                                 \
            for (int n = 0; n < 2; n++) {                                     \
                acc[QM * 4 + m][QN * 2 + n] = __builtin_amdgcn_mfma_f32_16x16x32_bf16( \
                    a0[m], b0[n], acc[QM * 4 + m][QN * 2 + n], 0, 0, 0);      \
                acc[QM * 4 + m][QN * 2 + n] = __builtin_amdgcn_mfma_f32_16x16x32_bf16( \
                    a1[m], b1[n], acc[QM * 4 + m][QN * 2 + n], 0, 0, 0);      \
            }                                                                 \
        __builtin_amdgcn_s_setprio(0);                                        \
        asm volatile(CLOSE ::: "memory");                                     \
    } while (0)

    // Prologue: 6 halves in ledger order (12 loads); vmcnt(8) -> U.A0,U.B0
    // landed (exactly what P1 reads); barrier makes that true for ALL waves.
    STAGEA(0, 0, 0); STAGEB(0, 0, 0);
    STAGEA(0, 1, 0); STAGEB(0, 1, 0);
    STAGEA(1, 0, 1); STAGEB(1, 0, 1);
    asm volatile("s_waitcnt vmcnt(8)\ns_barrier" ::: "memory");

    for (int i = 0; i < NITER - 1; i++) {
        int T = 2 * i;
        PHASE(0, 0, 0, STAGEA(1, 1, T + 1), "s_waitcnt lgkmcnt(0) vmcnt(6)\ns_barrier");
        PHASE(0, 0, 1, STAGEB(1, 1, T + 1), "s_waitcnt lgkmcnt(0)\ns_barrier");
        PHASE(0, 1, 0, STAGEA(0, 0, T + 2), "s_waitcnt lgkmcnt(0)\ns_barrier");
        PHASE(0, 1, 1, STAGEB(0, 0, T + 2), "s_waitcnt lgkmcnt(0) vmcnt(8)\ns_barrier");
        PHASE(1, 0, 0, STAGEA(0, 1, T + 2), "s_waitcnt lgkmcnt(0) vmcnt(6)\ns_barrier");
        PHASE(1, 0, 1, STAGEB(0, 1, T + 2), "s_waitcnt lgkmcnt(0)\ns_barrier");
        PHASE(1, 1, 0, STAGEA(1, 0, T + 3), "s_waitcnt lgkmcnt(0)\ns_barrier");
        PHASE(1, 1, 1, STAGEB(1, 0, T + 3), "s_waitcnt lgkmcnt(0) vmcnt(8)\ns_barrier");
    }
    // Peeled last iteration (T = KT-2): only V.A1/V.B1[KT-1] still staged.
    PHASE(0, 0, 0, STAGEA(1, 1, KT - 1), "s_waitcnt lgkmcnt(0) vmcnt(6)\ns_barrier");
    PHASE(0, 0, 1, STAGEB(1, 1, KT - 1), "s_waitcnt lgkmcnt(0)\ns_barrier");
    PHASE(0, 1, 0, (void)0,              "s_waitcnt lgkmcnt(0)\ns_barrier");
    PHASE(0, 1, 1, (void)0,              "s_waitcnt lgkmcnt(0) vmcnt(4)\ns_barrier");
    PHASE(1, 0, 0, (void)0,              "s_waitcnt lgkmcnt(0) vmcnt(0)\ns_barrier");
    PHASE(1, 0, 1, (void)0,              "s_waitcnt lgkmcnt(0)\ns_barrier");
    PHASE(1, 1, 0, (void)0,              "s_waitcnt lgkmcnt(0)\ns_barrier");
    PHASE(1, 1, 1, (void)0,              "s_waitcnt lgkmcnt(0)\ns_barrier");
#undef PHASE
#undef STAGEA
#undef STAGEB

    // C/D layout: col = lane&15, row = (lane>>4)*4 + reg  [m89/m91-verified]
    if (MODE == 0) {
        ushort_t* hp = (ushort_t*)Cout + (size_t)wi * 256 * HH;
#pragma unroll
        for (int mt = 0; mt < 8; mt++) {
#pragma unroll
            for (int r = 0; r < 4; r++) {
                int row = wave_m + mt * 16 + quad * 4 + r;
#pragma unroll
                for (int nt = 0; nt < 4; nt++) {
                    int col = col0 + wave_n + nt * 16 + lm;
                    hp[(size_t)row * HH + col] = f2bf(fmaxf(acc[mt][nt][r], 0.f));
                }
            }
        }
    } else {
        float* outp = (float*)Cout;
#pragma unroll
        for (int mt = 0; mt < 8; mt++) {
#pragma unroll
            for (int r = 0; r < 4; r++) {
                int row = wave_m + mt * 16 + quad * 4 + r;
                int slot = e * MM + ytile * 256 + row;
                int tok = s2t[slot];
                if (tok < 0) continue;
                float g = s2g[slot];
#pragma unroll
                for (int nt = 0; nt < 4; nt++) {
                    int col = col0 + wave_n + nt * 16 + lm;
                    atomicAdd(outp + (size_t)tok * DD + col, g * acc[mt][nt][r]);
                }
            }
        }
    }
}

// ---------------------------------------------------------------------------
// Workspace layout (bytes), total ~143.0 MB (< 151.2 MB proven):
//   0         e1 32768 | 32768 e2 | 65536 g1 | 98304 g2
//   131072    used (pad 1024)
//   132096    meta (5136 ints = 20544 B, pad to 20608)
//   152704    s2t  131072
//   283776    s2g  131072
//   414848    xbf  bf16 [8192][512]            =   8,388,608
//   8803456   wt   bf16 (w1t, then w2t)        =  33,554,432
//   42357888  hid  bf16 [96 strips][256][2048] = 100,663,296
// ---------------------------------------------------------------------------
extern "C" void kernel_launch(void* const* d_in, const int* in_sizes, int n_in,
                              void* d_out, int out_size, void* d_ws, size_t ws_size,
                              hipStream_t stream) {
    const float* x  = (const float*)d_in[0];
    const float* wg = (const float*)d_in[1];
    const float* w1 = (const float*)d_in[2];
    const float* w2 = (const float*)d_in[3];
    float* out = (float*)d_out;

    char* ws = (char*)d_ws;
    int*      e1   = (int*)(ws);
    int*      e2   = (int*)(ws + 32768);
    float*    g1   = (float*)(ws + 65536);
    float*    g2   = (float*)(ws + 98304);
    int*      used = (int*)(ws + 131072);
    int*      meta = (int*)(ws + 132096);
    int*      s2t  = (int*)(ws + 152704);
    float*    s2g  = (float*)(ws + 283776);
    ushort_t* xbf  = (ushort_t*)(ws + 414848);
    ushort_t* wt   = (ushort_t*)(ws + 8803456);
    ushort_t* hid  = (ushort_t*)(ws + 42357888);

    hipMemsetAsync(out, 0, (size_t)NTOK * DD * sizeof(float), stream);

    gating_kernel<<<NTOK / 4, 256, 0, stream>>>(x, wg, e1, e2, g1, g2, xbf);
    scan_kernel<<<BB * EE, 256, 0, stream>>>(e1, e2, g1, g2, s2t, s2g, used);
    schedule_kernel<<<1, 64, 0, stream>>>(used, meta);

    // GEMM1: gather(xbf) @ w1t -> relu -> hid (compact 256-strips), XCD-pinned
    transpose_bf16<<<dim3(HH / 32, DD / 32, EE), dim3(32, 8), 0, stream>>>(w1, wt, DD, HH);
    gemm_mfma<0><<<dim3(8, 128), 512, 0, stream>>>(xbf, wt, hid, meta, s2t, s2g);

    // GEMM2: hid @ w2t (split-K 2) -> gate-weighted scatter-add, XCD-pinned
    transpose_bf16<<<dim3(DD / 32, HH / 32, EE), dim3(32, 8), 0, stream>>>(w2, wt, HH, DD);
    gemm_mfma<1><<<dim3(8, 64), 512, 0, stream>>>(hid, wt, out, meta, s2t, s2g);
}

// Round 6
// 352.723 us; speedup vs baseline: 1.1895x; 1.1895x over previous
//
#include <hip/hip_runtime.h>

// Problem constants (from reference setup_inputs)
#define BB 2
#define NN 4096
#define DD 512
#define EE 16
#define HH 2048
#define CAP 1024            // capacity = int((4096*2)*2.0/16) = 1024
#define NTOK (BB*NN)        // 8192
#define MM (BB*CAP)         // 2048 = per-expert logical M
#define MAXSTRIP 160        // worst-case total 128-row strips (<=158)

typedef unsigned short ushort_t;
typedef __attribute__((ext_vector_type(8))) short bf16x8;   // 8 bf16 = 4 VGPRs
typedef __attribute__((ext_vector_type(4))) float floatx4;  // MFMA accumulator

// round-to-nearest-even f32 -> bf16 bit pattern
__device__ __forceinline__ ushort_t f2bf(float f) {
    union { float f; unsigned u; } v; v.f = f;
    unsigned r = v.u + 0x7fffu + ((v.u >> 16) & 1u);
    return (ushort_t)(r >> 16);
}

// async global->LDS, 16B per lane (global_load_lds_dwordx4).
__device__ __forceinline__ void cp16(const void* g, void* l) {
    __builtin_amdgcn_global_load_lds(
        (const __attribute__((address_space(1))) void*)g,
        (__attribute__((address_space(3))) void*)l, 16, 0, 0);
}

// ---------------------------------------------------------------------------
// Kernel 1: gating (f32-exact selection) + fused bf16 conversion of x.
// ---------------------------------------------------------------------------
__launch_bounds__(256)
__global__ void gating_kernel(const float* __restrict__ x,
                              const float* __restrict__ wg,
                              int* __restrict__ e1, int* __restrict__ e2,
                              float* __restrict__ g1, float* __restrict__ g2,
                              ushort_t* __restrict__ xbf) {
    int wave = threadIdx.x >> 6;
    int lane = threadIdx.x & 63;
    int t = blockIdx.x * 4 + wave;
    const float* xp = x + (size_t)t * DD;

    float4 xa = ((const float4*)xp)[lane * 2];
    float4 xb = ((const float4*)xp)[lane * 2 + 1];
    float xs[8] = {xa.x, xa.y, xa.z, xa.w, xb.x, xb.y, xb.z, xb.w};

    ushort4 h0, h1;
    h0.x = f2bf(xs[0]); h0.y = f2bf(xs[1]); h0.z = f2bf(xs[2]); h0.w = f2bf(xs[3]);
    h1.x = f2bf(xs[4]); h1.y = f2bf(xs[5]); h1.z = f2bf(xs[6]); h1.w = f2bf(xs[7]);
    ushort4* xo = (ushort4*)(xbf + (size_t)t * DD);
    xo[lane * 2] = h0; xo[lane * 2 + 1] = h1;

    float acc[EE];
#pragma unroll
    for (int e = 0; e < EE; e++) acc[e] = 0.f;
    int d0 = lane * 8;
#pragma unroll
    for (int j = 0; j < 8; j++) {
        const float* wrow = wg + (d0 + j) * EE;
#pragma unroll
        for (int e = 0; e < EE; e++) acc[e] = fmaf(xs[j], wrow[e], acc[e]);
    }
#pragma unroll
    for (int off = 32; off > 0; off >>= 1) {
#pragma unroll
        for (int e = 0; e < EE; e++) acc[e] += __shfl_xor(acc[e], off, 64);
    }
    if (lane == 0) {
        float m = acc[0];
#pragma unroll
        for (int e = 1; e < EE; e++) m = fmaxf(m, acc[e]);
        float p[EE]; float s = 0.f;
#pragma unroll
        for (int e = 0; e < EE; e++) { p[e] = __expf(acc[e] - m); s += p[e]; }
        float inv = 1.f / s;
#pragma unroll
        for (int e = 0; e < EE; e++) p[e] *= inv;
        int i1 = 0; float v1 = p[0];
#pragma unroll
        for (int e = 1; e < EE; e++) if (p[e] > v1) { v1 = p[e]; i1 = e; }
        int i2 = (i1 == 0) ? 1 : 0; float v2 = p[i2];
#pragma unroll
        for (int e = 0; e < EE; e++)
            if (e != i1 && p[e] > v2) { v2 = p[e]; i2 = e; }
        float denom = v1 + v2 + 1e-9f;
        e1[t] = i1; e2[t] = i2;
        g1[t] = v1 / denom; g2[t] = v2 / denom;
    }
}

// ---------------------------------------------------------------------------
// Kernel 2: per-(b,e) exclusive scan -> slot assignment with capacity drop.
// Wave-shuffle scan (1 barrier vs 16). Order-preserving: prefix by tid then
// j-order within thread == token order. Writes s2t (token or -1 for ALL CAP
// slots), s2g, used[e][b].
// ---------------------------------------------------------------------------
__launch_bounds__(256)
__global__ void scan_kernel(const int* __restrict__ e1, const int* __restrict__ e2,
                            const float* __restrict__ g1, const float* __restrict__ g2,
                            int* __restrict__ s2t, float* __restrict__ s2g,
                            int* __restrict__ used) {
    int b = blockIdx.x / EE;
    int e = blockIdx.x % EE;
    int tid = threadIdx.x;
    int lane = tid & 63;
    int w = tid >> 6;
    const int base = b * NN;
    int n0 = tid * 16;

    unsigned m1 = 0, m2 = 0;
    int c1 = 0, c2 = 0;
#pragma unroll
    for (int j = 0; j < 16; j++) {
        int n = n0 + j;
        if (e1[base + n] == e) { m1 |= 1u << j; c1++; }
        if (e2[base + n] == e) { m2 |= 1u << j; c2++; }
    }
    // in-wave inclusive scans (no barriers)
    int i1 = c1, i2 = c2;
#pragma unroll
    for (int off = 1; off < 64; off <<= 1) {
        int t1 = __shfl_up(i1, off, 64);
        int t2 = __shfl_up(i2, off, 64);
        if (lane >= off) { i1 += t1; i2 += t2; }
    }
    __shared__ int ws1[4], ws2[4];
    if (lane == 63) { ws1[w] = i1; ws2[w] = i2; }
    __syncthreads();
    int p1 = 0, p2 = 0, total1 = 0, total2 = 0;
#pragma unroll
    for (int k = 0; k < 4; k++) {
        int v1 = ws1[k], v2 = ws2[k];
        if (k < w) { p1 += v1; p2 += v2; }
        total1 += v1; total2 += v2;
    }
    int kept1 = min(total1, CAP);
    int ex1 = p1 + i1 - c1;                 // block-exclusive prefix, list 1
    int ex2 = p2 + i2 - c2 + kept1;         // list 2 starts after kept list-1
    const int sbase = (e * BB + b) * CAP;
#pragma unroll
    for (int j = 0; j < 16; j++) {
        int n = n0 + j;
        if (m1 & (1u << j)) {
            if (ex1 < CAP) { s2t[sbase + ex1] = base + n; s2g[sbase + ex1] = g1[base + n]; }
            ex1++;
        }
        if (m2 & (1u << j)) {
            if (ex2 < CAP) { s2t[sbase + ex2] = base + n; s2g[sbase + ex2] = g2[base + n]; }
            ex2++;
        }
    }
    int kept2 = min(total2, max(0, CAP - kept1));
    int u = kept1 + kept2;
    if (tid == 0) used[e * BB + b] = u;
    // emits cover [0, u); fill the rest (disjoint -> no extra barrier needed)
    for (int i = u + tid; i < CAP; i += 256) s2t[sbase + i] = -1;
}

// ---------------------------------------------------------------------------
// Kernel 3: build XCD-pinned job schedules. Expert e is pinned to XCD e&7
// (two experts per XCD). With grid (8, slots), linear block id = x + 8*y, and
// round-robin dispatch puts all blocks with blockIdx.x == x on XCD x, so each
// XCD's L2 only holds its 2 experts' weight slabs + A rows.
// meta layout (ints): [0..7] count1/xcd, [8..15] count2/xcd,
//                     [16..4111] sched1 (8 x 512), [4112..5135] sched2 (8 x 128)
// job = (e<<17) | (wi<<9) | (ytile<<5) | col   (wi = global compact strip id)
// ---------------------------------------------------------------------------
__global__ void schedule_kernel(const int* __restrict__ used, int* __restrict__ meta) {
    __shared__ int ns[32], pre[32];
    int i = threadIdx.x;
    if (i < 32) {
        int e = i >> 1, b = i & 1;
        ns[i] = (used[e * BB + b] + 127) >> 7;
    }
    __syncthreads();
    if (i == 0) {
        int acc = 0;
        for (int j = 0; j < 32; j++) { pre[j] = acc; acc += ns[j]; }
    }
    __syncthreads();
    if (i < 16) {
        int e = i;
        int xcd = e & 7;
        int mine  = ns[2 * e] + ns[2 * e + 1];
        int po    = (e < 8) ? (e + 8) : (e - 8);
        int other = ns[2 * po] + ns[2 * po + 1];
        if (e < 8) {
            meta[xcd]     = (mine + other) * 16;   // GEMM1 jobs on this XCD
            meta[8 + xcd] = (mine + other) * 4;    // GEMM2 jobs on this XCD
        }
        int off = (e < 8) ? 0 : other;             // partner's jobs come first
        int* sc1 = meta + 16 + xcd * 512 + off * 16;
        int j = 0;
        for (int col = 0; col < 16; col++)
            for (int bb = 0; bb < 2; bb++)
                for (int s = 0; s < ns[2 * e + bb]; s++) {
                    int wi = pre[2 * e + bb] + s;
                    sc1[j++] = (e << 17) | (wi << 9) | ((bb * 8 + s) << 5) | col;
                }
        int* sc2 = meta + 16 + 4096 + xcd * 128 + off * 4;
        j = 0;
        for (int col = 0; col < 4; col++)
            for (int bb = 0; bb < 2; bb++)
                for (int s = 0; s < ns[2 * e + bb]; s++) {
                    int wi = pre[2 * e + bb] + s;
                    sc2[j++] = (e << 17) | (wi << 9) | ((bb * 8 + s) << 5) | col;
                }
    }
}

// ---------------------------------------------------------------------------
// Kernel 4: per-expert transpose + bf16: in f32 [E][R][C] -> out bf16 [E][C][R].
// ---------------------------------------------------------------------------
__global__ void transpose_bf16(const float* __restrict__ in,
                               ushort_t* __restrict__ outp, int R, int C) {
    __shared__ float tile[32][33];
    const float* slab = in + (size_t)blockIdx.z * R * C;
    ushort_t* oslab = outp + (size_t)blockIdx.z * R * C;
    int c0 = blockIdx.x * 32, r0 = blockIdx.y * 32;
    int tx = threadIdx.x, ty = threadIdx.y;   // (32, 8)
#pragma unroll
    for (int j = 0; j < 4; j++)
        tile[ty + j * 8][tx] = slab[(size_t)(r0 + ty + j * 8) * C + c0 + tx];
    __syncthreads();
#pragma unroll
    for (int j = 0; j < 4; j++)
        oslab[(size_t)(c0 + ty + j * 8) * R + r0 + tx] = f2bf(tile[tx][ty + j * 8]);
}

// ---------------------------------------------------------------------------
// Kernel 5: bf16 MFMA GEMM, 128x128 tile, BK=32, XCD-pinned job schedule,
// 3-stage software pipeline (prefetch distance 2, counted vmcnt(8) never
// drained in steady state), XOR-swizzled staging (0 bank conflicts).
// Read-complete barrier placed BEFORE the MFMA cluster so MFMAs overlap the
// next iteration's stage issue in other waves.
//   MODE 0 (GEMM1): K=512,  A gathered from xbf via s2t, relu -> hid[strip].
//   MODE 1 (GEMM2): K=2048, A = hid[strip], epilogue gate*acc atomicAdd -> out.
// ---------------------------------------------------------------------------
template <int MODE>
__launch_bounds__(256)
__global__ void gemm_mfma(const ushort_t* __restrict__ Abase,
                          const ushort_t* __restrict__ Bt,
                          void* __restrict__ Cout,
                          const int* __restrict__ meta,
                          const int* __restrict__ s2t,
                          const float* __restrict__ s2g) {
    constexpr int K = (MODE == 0) ? DD : HH;
    constexpr int KITERS = K / 32;

    int xcd = blockIdx.x;
    if ((int)blockIdx.y >= meta[(MODE == 0 ? 0 : 8) + xcd]) return;
    int job = meta[16 + (MODE == 0 ? 0 : 4096) + xcd * (MODE == 0 ? 512 : 128) + blockIdx.y];
    int col0  = (job & 31) * 128;
    int ytile = (job >> 5) & 15;
    int wi    = (job >> 9) & 255;
    int e     = job >> 17;

    // 3-stage pipeline: 3 x (8KB A + 8KB B) = 48KB -> 3 blocks/CU
    __shared__ ushort_t As[3][128 * 32];
    __shared__ ushort_t Bs[3][128 * 32];

    int tid = threadIdx.x;
    int lane = tid & 63;
    int wid = tid >> 6;
    int wave_m = (wid & 1) << 6;
    int wave_n = (wid >> 1) << 6;
    int lm = lane & 15;
    int quad = lane >> 4;
    // fragment-read swizzle: global chunk (r, c) stored at LDS col c ^ ((r>>1)&3)
    int sw = (quad ^ ((lm >> 1) & 3)) * 8;

    // per-thread global chunk base pointers (k = 0)
    const ushort_t* ga[2];
    const ushort_t* gb[2];
#pragma unroll
    for (int it = 0; it < 2; it++) {
        int idx = it * 256 + tid;
        int r = idx >> 2;
        int cg = (idx & 3) ^ ((r >> 1) & 3);
        if (MODE == 0) {
            int tok = s2t[e * MM + ytile * 128 + r];
            if (tok < 0) tok = 0;   // dummy valid row; masked at epilogue
            ga[it] = Abase + (size_t)tok * DD + cg * 8;
        } else {
            ga[it] = Abase + (size_t)(wi * 128 + r) * HH + cg * 8;
        }
        gb[it] = Bt + (size_t)e * HH * DD + (size_t)(col0 + r) * K + cg * 8;
    }

    auto stage = [&](int buf, int ki) {
#pragma unroll
        for (int it = 0; it < 2; it++)
            cp16(ga[it] + ki * 32, &As[buf][(it * 256 + tid) * 8]);
#pragma unroll
        for (int it = 0; it < 2; it++)
            cp16(gb[it] + ki * 32, &Bs[buf][(it * 256 + tid) * 8]);
    };

    floatx4 acc[4][4];
#pragma unroll
    for (int i = 0; i < 4; i++)
#pragma unroll
        for (int j = 0; j < 4; j++)
            acc[i][j] = (floatx4)(0.f);

    // Prologue: two tiles in flight.
    stage(0, 0);
    stage(1, 1);

    // One K-step; CUR/NXT are literal constants at every expansion so LDS
    // bases are compile-time. vmcnt(8): stages ki+1, ki+2 (4 loads each)
    // remain in flight while the oldest 4 (stage ki) have landed -> buffer
    // CUR is ready after the barrier. The lgkmcnt(0)+barrier BEFORE the MFMA
    // cluster releases buf CUR for overwrite while MFMAs (register-only)
    // still execute, overlapping other waves' next stage issue.
#define KSTEP(CUR, NXT, KI)                                                     \
    do {                                                                        \
        int ki_ = (KI);                                                         \
        if (ki_ + 2 < KITERS) {                                                 \
            stage(NXT, ki_ + 2);                                                \
            asm volatile("s_waitcnt vmcnt(8)\ns_barrier" ::: "memory");         \
        } else if (ki_ + 2 == KITERS) {                                         \
            asm volatile("s_waitcnt vmcnt(4)\ns_barrier" ::: "memory");         \
        } else {                                                                \
            asm volatile("s_waitcnt vmcnt(0)\ns_barrier" ::: "memory");         \
        }                                                                       \
        bf16x8 af[4], bfr[4];                                                   \
        _Pragma("unroll")                                                       \
        for (int mt = 0; mt < 4; mt++)                                          \
            af[mt] = *(const bf16x8*)&As[CUR][(wave_m + mt * 16 + lm) * 32 + sw]; \
        _Pragma("unroll")                                                       \
        for (int nt = 0; nt < 4; nt++)                                          \
            bfr[nt] = *(const bf16x8*)&Bs[CUR][(wave_n + nt * 16 + lm) * 32 + sw]; \
        asm volatile("s_waitcnt lgkmcnt(0)\ns_barrier" ::: "memory");           \
        _Pragma("unroll")                                                       \
        for (int mt = 0; mt < 4; mt++)                                          \
            _Pragma("unroll")                                                   \
            for (int nt = 0; nt < 4; nt++)                                      \
                acc[mt][nt] = __builtin_amdgcn_mfma_f32_16x16x32_bf16(          \
                    af[mt], bfr[nt], acc[mt][nt], 0, 0, 0);                     \
    } while (0)

    for (int kb = 0; kb < KITERS; kb += 3) {
        KSTEP(0, 2, kb);
        if (kb + 1 < KITERS) KSTEP(1, 0, kb + 1);
        if (kb + 2 < KITERS) KSTEP(2, 1, kb + 2);
    }
#undef KSTEP

    // C/D layout: col = lane&15, row = (lane>>4)*4 + reg  [m89/m91-verified]
    if (MODE == 0) {
        ushort_t* hp = (ushort_t*)Cout + (size_t)wi * 128 * HH;
#pragma unroll
        for (int mt = 0; mt < 4; mt++) {
#pragma unroll
            for (int r = 0; r < 4; r++) {
                int row = wave_m + mt * 16 + quad * 4 + r;
#pragma unroll
                for (int nt = 0; nt < 4; nt++) {
                    int col = col0 + wave_n + nt * 16 + lm;
                    hp[(size_t)row * HH + col] = f2bf(fmaxf(acc[mt][nt][r], 0.f));
                }
            }
        }
    } else {
        float* outp = (float*)Cout;
#pragma unroll
        for (int mt = 0; mt < 4; mt++) {
#pragma unroll
            for (int r = 0; r < 4; r++) {
                int row = wave_m + mt * 16 + quad * 4 + r;
                int slot = e * MM + ytile * 128 + row;
                int tok = s2t[slot];
                if (tok < 0) continue;
                float g = s2g[slot];
#pragma unroll
                for (int nt = 0; nt < 4; nt++) {
                    int col = col0 + wave_n + nt * 16 + lm;
                    atomicAdd(outp + (size_t)tok * DD + col, g * acc[mt][nt][r]);
                }
            }
        }
    }
}

// ---------------------------------------------------------------------------
// Workspace layout (bytes), total ~126.2 MB (< 151.2 MB proven):
//   0         e1 32768 | 32768 e2 | 65536 g1 | 98304 g2
//   131072    used (pad 1024)
//   132096    meta (5136 ints = 20544 B, pad to 20608)
//   152704    s2t  131072
//   283776    s2g  131072
//   414848    xbf  bf16 [8192][512]            =  8,388,608
//   8803456   wt   bf16 (w1t, then w2t)        = 33,554,432
//   42357888  hid  bf16 [160 strips][128][2048]= 83,886,080
// ---------------------------------------------------------------------------
extern "C" void kernel_launch(void* const* d_in, const int* in_sizes, int n_in,
                              void* d_out, int out_size, void* d_ws, size_t ws_size,
                              hipStream_t stream) {
    const float* x  = (const float*)d_in[0];
    const float* wg = (const float*)d_in[1];
    const float* w1 = (const float*)d_in[2];
    const float* w2 = (const float*)d_in[3];
    float* out = (float*)d_out;

    char* ws = (char*)d_ws;
    int*      e1   = (int*)(ws);
    int*      e2   = (int*)(ws + 32768);
    float*    g1   = (float*)(ws + 65536);
    float*    g2   = (float*)(ws + 98304);
    int*      used = (int*)(ws + 131072);
    int*      meta = (int*)(ws + 132096);
    int*      s2t  = (int*)(ws + 152704);
    float*    s2g  = (float*)(ws + 283776);
    ushort_t* xbf  = (ushort_t*)(ws + 414848);
    ushort_t* wt   = (ushort_t*)(ws + 8803456);
    ushort_t* hid  = (ushort_t*)(ws + 42357888);

    hipMemsetAsync(out, 0, (size_t)NTOK * DD * sizeof(float), stream);

    gating_kernel<<<NTOK / 4, 256, 0, stream>>>(x, wg, e1, e2, g1, g2, xbf);
    scan_kernel<<<BB * EE, 256, 0, stream>>>(e1, e2, g1, g2, s2t, s2g, used);
    schedule_kernel<<<1, 64, 0, stream>>>(used, meta);

    // GEMM1: gather(xbf) @ w1t -> relu -> hid (compact strips), XCD-pinned
    transpose_bf16<<<dim3(HH / 32, DD / 32, EE), dim3(32, 8), 0, stream>>>(w1, wt, DD, HH);
    gemm_mfma<0><<<dim3(8, 512), 256, 0, stream>>>(xbf, wt, hid, meta, s2t, s2g);

    // GEMM2: hid @ w2t -> gate-weighted scatter-add into out, XCD-pinned
    transpose_bf16<<<dim3(DD / 32, HH / 32, EE), dim3(32, 8), 0, stream>>>(w2, wt, HH, DD);
    gemm_mfma<1><<<dim3(8, 128), 256, 0, stream>>>(hid, wt, out, meta, s2t, s2g);
}

// Round 8
// 350.751 us; speedup vs baseline: 1.1962x; 1.0056x over previous
//
#include <hip/hip_runtime.h>

// Problem constants (from reference setup_inputs)
#define BB 2
#define NN 4096
#define DD 512
#define EE 16
#define HH 2048
#define CAP 1024            // capacity = int((4096*2)*2.0/16) = 1024
#define NTOK (BB*NN)        // 8192
#define MM (BB*CAP)         // 2048 = per-expert logical M
#define MAXSTRIP 160        // worst-case total 128-row strips (<=158)

typedef unsigned short ushort_t;
typedef __attribute__((ext_vector_type(8))) short bf16x8;   // 8 bf16 = 4 VGPRs
typedef __attribute__((ext_vector_type(4))) float floatx4;  // MFMA accumulator

// round-to-nearest-even f32 -> bf16 bit pattern
__device__ __forceinline__ ushort_t f2bf(float f) {
    union { float f; unsigned u; } v; v.f = f;
    unsigned r = v.u + 0x7fffu + ((v.u >> 16) & 1u);
    return (ushort_t)(r >> 16);
}

// async global->LDS, 16B per lane (global_load_lds_dwordx4).
__device__ __forceinline__ void cp16(const void* g, void* l) {
    __builtin_amdgcn_global_load_lds(
        (const __attribute__((address_space(1))) void*)g,
        (__attribute__((address_space(3))) void*)l, 16, 0, 0);
}

// ---------------------------------------------------------------------------
// Kernel 1: gating (f32-exact selection) + fused bf16 conversion of x.
// ---------------------------------------------------------------------------
__launch_bounds__(256)
__global__ void gating_kernel(const float* __restrict__ x,
                              const float* __restrict__ wg,
                              int* __restrict__ e1, int* __restrict__ e2,
                              float* __restrict__ g1, float* __restrict__ g2,
                              ushort_t* __restrict__ xbf) {
    int wave = threadIdx.x >> 6;
    int lane = threadIdx.x & 63;
    int t = blockIdx.x * 4 + wave;
    const float* xp = x + (size_t)t * DD;

    float4 xa = ((const float4*)xp)[lane * 2];
    float4 xb = ((const float4*)xp)[lane * 2 + 1];
    float xs[8] = {xa.x, xa.y, xa.z, xa.w, xb.x, xb.y, xb.z, xb.w};

    ushort4 h0, h1;
    h0.x = f2bf(xs[0]); h0.y = f2bf(xs[1]); h0.z = f2bf(xs[2]); h0.w = f2bf(xs[3]);
    h1.x = f2bf(xs[4]); h1.y = f2bf(xs[5]); h1.z = f2bf(xs[6]); h1.w = f2bf(xs[7]);
    ushort4* xo = (ushort4*)(xbf + (size_t)t * DD);
    xo[lane * 2] = h0; xo[lane * 2 + 1] = h1;

    float acc[EE];
#pragma unroll
    for (int e = 0; e < EE; e++) acc[e] = 0.f;
    int d0 = lane * 8;
#pragma unroll
    for (int j = 0; j < 8; j++) {
        const float* wrow = wg + (d0 + j) * EE;
#pragma unroll
        for (int e = 0; e < EE; e++) acc[e] = fmaf(xs[j], wrow[e], acc[e]);
    }
#pragma unroll
    for (int off = 32; off > 0; off >>= 1) {
#pragma unroll
        for (int e = 0; e < EE; e++) acc[e] += __shfl_xor(acc[e], off, 64);
    }
    if (lane == 0) {
        float m = acc[0];
#pragma unroll
        for (int e = 1; e < EE; e++) m = fmaxf(m, acc[e]);
        float p[EE]; float s = 0.f;
#pragma unroll
        for (int e = 0; e < EE; e++) { p[e] = __expf(acc[e] - m); s += p[e]; }
        float inv = 1.f / s;
#pragma unroll
        for (int e = 0; e < EE; e++) p[e] *= inv;
        int i1 = 0; float v1 = p[0];
#pragma unroll
        for (int e = 1; e < EE; e++) if (p[e] > v1) { v1 = p[e]; i1 = e; }
        int i2 = (i1 == 0) ? 1 : 0; float v2 = p[i2];
#pragma unroll
        for (int e = 0; e < EE; e++)
            if (e != i1 && p[e] > v2) { v2 = p[e]; i2 = e; }
        float denom = v1 + v2 + 1e-9f;
        e1[t] = i1; e2[t] = i2;
        g1[t] = v1 / denom; g2[t] = v2 / denom;
    }
}

// ---------------------------------------------------------------------------
// Kernel 2: per-(b,e) exclusive scan -> slot assignment with capacity drop.
// Wave-shuffle scan (1 barrier). Order-preserving: prefix by tid then j-order
// within thread == token order. Writes s2t (token or -1 for ALL CAP slots),
// s2g, used[e][b].
// ---------------------------------------------------------------------------
__launch_bounds__(256)
__global__ void scan_kernel(const int* __restrict__ e1, const int* __restrict__ e2,
                            const float* __restrict__ g1, const float* __restrict__ g2,
                            int* __restrict__ s2t, float* __restrict__ s2g,
                            int* __restrict__ used) {
    int b = blockIdx.x / EE;
    int e = blockIdx.x % EE;
    int tid = threadIdx.x;
    int lane = tid & 63;
    int w = tid >> 6;
    const int base = b * NN;
    int n0 = tid * 16;

    unsigned m1 = 0, m2 = 0;
    int c1 = 0, c2 = 0;
#pragma unroll
    for (int j = 0; j < 16; j++) {
        int n = n0 + j;
        if (e1[base + n] == e) { m1 |= 1u << j; c1++; }
        if (e2[base + n] == e) { m2 |= 1u << j; c2++; }
    }
    // in-wave inclusive scans (no barriers)
    int i1 = c1, i2 = c2;
#pragma unroll
    for (int off = 1; off < 64; off <<= 1) {
        int t1 = __shfl_up(i1, off, 64);
        int t2 = __shfl_up(i2, off, 64);
        if (lane >= off) { i1 += t1; i2 += t2; }
    }
    __shared__ int ws1[4], ws2[4];
    if (lane == 63) { ws1[w] = i1; ws2[w] = i2; }
    __syncthreads();
    int p1 = 0, p2 = 0, total1 = 0, total2 = 0;
#pragma unroll
    for (int k = 0; k < 4; k++) {
        int v1 = ws1[k], v2 = ws2[k];
        if (k < w) { p1 += v1; p2 += v2; }
        total1 += v1; total2 += v2;
    }
    int kept1 = min(total1, CAP);
    int ex1 = p1 + i1 - c1;                 // block-exclusive prefix, list 1
    int ex2 = p2 + i2 - c2 + kept1;         // list 2 starts after kept list-1
    const int sbase = (e * BB + b) * CAP;
#pragma unroll
    for (int j = 0; j < 16; j++) {
        int n = n0 + j;
        if (m1 & (1u << j)) {
            if (ex1 < CAP) { s2t[sbase + ex1] = base + n; s2g[sbase + ex1] = g1[base + n]; }
            ex1++;
        }
        if (m2 & (1u << j)) {
            if (ex2 < CAP) { s2t[sbase + ex2] = base + n; s2g[sbase + ex2] = g2[base + n]; }
            ex2++;
        }
    }
    int kept2 = min(total2, max(0, CAP - kept1));
    int u = kept1 + kept2;
    if (tid == 0) used[e * BB + b] = u;
    // emits cover [0, u); fill the rest (disjoint -> no extra barrier needed)
    for (int i = u + tid; i < CAP; i += 256) s2t[sbase + i] = -1;
}

// ---------------------------------------------------------------------------
// Kernel 3: build XCD-pinned job schedules. Expert e is pinned to XCD e&7
// (two experts per XCD). With grid (8, slots), linear block id = x + 8*y, and
// round-robin dispatch puts all blocks with blockIdx.x == x on XCD x, so each
// XCD's L2 only holds its 2 experts' weight slabs + A rows.
// meta layout (ints): [0..7] count1/xcd, [8..15] count2/xcd,
//                     [16..4111] sched1 (8 x 512), [4112..5135] sched2 (8 x 128)
// job = (e<<17) | (wi<<9) | (ytile<<5) | col   (wi = global compact strip id)
// ---------------------------------------------------------------------------
__global__ void schedule_kernel(const int* __restrict__ used, int* __restrict__ meta) {
    __shared__ int ns[32], pre[32];
    int i = threadIdx.x;
    if (i < 32) {
        int e = i >> 1, b = i & 1;
        ns[i] = (used[e * BB + b] + 127) >> 7;
    }
    __syncthreads();
    if (i == 0) {
        int acc = 0;
        for (int j = 0; j < 32; j++) { pre[j] = acc; acc += ns[j]; }
    }
    __syncthreads();
    if (i < 16) {
        int e = i;
        int xcd = e & 7;
        int mine  = ns[2 * e] + ns[2 * e + 1];
        int po    = (e < 8) ? (e + 8) : (e - 8);
        int other = ns[2 * po] + ns[2 * po + 1];
        if (e < 8) {
            meta[xcd]     = (mine + other) * 16;   // GEMM1 jobs on this XCD
            meta[8 + xcd] = (mine + other) * 4;    // GEMM2 jobs on this XCD
        }
        int off = (e < 8) ? 0 : other;             // partner's jobs come first
        int* sc1 = meta + 16 + xcd * 512 + off * 16;
        int j = 0;
        for (int col = 0; col < 16; col++)
            for (int bb = 0; bb < 2; bb++)
                for (int s = 0; s < ns[2 * e + bb]; s++) {
                    int wi = pre[2 * e + bb] + s;
                    sc1[j++] = (e << 17) | (wi << 9) | ((bb * 8 + s) << 5) | col;
                }
        int* sc2 = meta + 16 + 4096 + xcd * 128 + off * 4;
        j = 0;
        for (int col = 0; col < 4; col++)
            for (int bb = 0; bb < 2; bb++)
                for (int s = 0; s < ns[2 * e + bb]; s++) {
                    int wi = pre[2 * e + bb] + s;
                    sc2[j++] = (e << 17) | (wi << 9) | ((bb * 8 + s) << 5) | col;
                }
    }
}

// ---------------------------------------------------------------------------
// Kernel 4: per-expert transpose + bf16: in f32 [E][R][C] -> out bf16 [E][C][R].
// 64x64 tiles, float4 loads (256B/16-lane group), LDS [64][65] (2-way bank
// aliasing = free), ushort4 stores (128B/16-lane group). Grid (C/64, R/64, E).
// ---------------------------------------------------------------------------
__launch_bounds__(256)
__global__ void transpose_bf16(const float* __restrict__ in,
                               ushort_t* __restrict__ outp, int R, int C) {
    __shared__ float tile[64][65];
    const float* slab = in + (size_t)blockIdx.z * R * C;
    ushort_t* oslab = outp + (size_t)blockIdx.z * R * C;
    int c0 = blockIdx.x * 64, r0 = blockIdx.y * 64;
    int tid = threadIdx.x;
    int rr = tid >> 4;          // 0..15
    int cc = tid & 15;          // 0..15
#pragma unroll
    for (int j = 0; j < 4; j++) {
        int row = rr + j * 16;
        float4 v = *(const float4*)(slab + (size_t)(r0 + row) * C + c0 + cc * 4);
        tile[row][cc * 4 + 0] = v.x;
        tile[row][cc * 4 + 1] = v.y;
        tile[row][cc * 4 + 2] = v.z;
        tile[row][cc * 4 + 3] = v.w;
    }
    __syncthreads();
#pragma unroll
    for (int j = 0; j < 4; j++) {
        int trow = rr + j * 16;              // = original col within tile
        ushort4 h;
        h.x = f2bf(tile[cc * 4 + 0][trow]);
        h.y = f2bf(tile[cc * 4 + 1][trow]);
        h.z = f2bf(tile[cc * 4 + 2][trow]);
        h.w = f2bf(tile[cc * 4 + 3][trow]);
        *(ushort4*)(oslab + (size_t)(c0 + trow) * R + r0 + cc * 4) = h;
    }
}

// ---------------------------------------------------------------------------
// Kernel 5: bf16 MFMA GEMM, 128x128 tile, BK=32, XCD-pinned job schedule,
// 3-stage software pipeline (prefetch distance 2, counted vmcnt(8) never
// drained in steady state), XOR-swizzled staging (0 bank conflicts).
// Read-complete barrier placed BEFORE the MFMA cluster so MFMAs overlap the
// next iteration's stage issue in other waves.
//   MODE 0 (GEMM1): K=512,  A gathered from xbf via s2t, relu -> hid[strip].
//   MODE 1 (GEMM2): K=2048, A = hid[strip], epilogue gate*acc atomicAdd -> out.
// ---------------------------------------------------------------------------
template <int MODE>
__launch_bounds__(256)
__global__ void gemm_mfma(const ushort_t* __restrict__ Abase,
                          const ushort_t* __restrict__ Bt,
                          void* __restrict__ Cout,
                          const int* __restrict__ meta,
                          const int* __restrict__ s2t,
                          const float* __restrict__ s2g) {
    constexpr int K = (MODE == 0) ? DD : HH;
    constexpr int KITERS = K / 32;

    int xcd = blockIdx.x;
    if ((int)blockIdx.y >= meta[(MODE == 0 ? 0 : 8) + xcd]) return;
    int job = meta[16 + (MODE == 0 ? 0 : 4096) + xcd * (MODE == 0 ? 512 : 128) + blockIdx.y];
    int col0  = (job & 31) * 128;
    int ytile = (job >> 5) & 15;
    int wi    = (job >> 9) & 255;
    int e     = job >> 17;

    // 3-stage pipeline: 3 x (8KB A + 8KB B) = 48KB -> 3 blocks/CU
    __shared__ ushort_t As[3][128 * 32];
    __shared__ ushort_t Bs[3][128 * 32];

    int tid = threadIdx.x;
    int lane = tid & 63;
    int wid = tid >> 6;
    int wave_m = (wid & 1) << 6;
    int wave_n = (wid >> 1) << 6;
    int lm = lane & 15;
    int quad = lane >> 4;
    // fragment-read swizzle: global chunk (r, c) stored at LDS col c ^ ((r>>1)&3)
    int sw = (quad ^ ((lm >> 1) & 3)) * 8;

    // per-thread global chunk base pointers (k = 0)
    const ushort_t* ga[2];
    const ushort_t* gb[2];
#pragma unroll
    for (int it = 0; it < 2; it++) {
        int idx = it * 256 + tid;
        int r = idx >> 2;
        int cg = (idx & 3) ^ ((r >> 1) & 3);
        if (MODE == 0) {
            int tok = s2t[e * MM + ytile * 128 + r];
            if (tok < 0) tok = 0;   // dummy valid row; masked at epilogue
            ga[it] = Abase + (size_t)tok * DD + cg * 8;
        } else {
            ga[it] = Abase + (size_t)(wi * 128 + r) * HH + cg * 8;
        }
        gb[it] = Bt + (size_t)e * HH * DD + (size_t)(col0 + r) * K + cg * 8;
    }

    auto stage = [&](int buf, int ki) {
#pragma unroll
        for (int it = 0; it < 2; it++)
            cp16(ga[it] + ki * 32, &As[buf][(it * 256 + tid) * 8]);
#pragma unroll
        for (int it = 0; it < 2; it++)
            cp16(gb[it] + ki * 32, &Bs[buf][(it * 256 + tid) * 8]);
    };

    floatx4 acc[4][4];
#pragma unroll
    for (int i = 0; i < 4; i++)
#pragma unroll
        for (int j = 0; j < 4; j++)
            acc[i][j] = (floatx4)(0.f);

    // Prologue: two tiles in flight.
    stage(0, 0);
    stage(1, 1);

    // One K-step; CUR/NXT are literal constants at every expansion so LDS
    // bases are compile-time. vmcnt(8): stages ki+1, ki+2 (4 loads each)
    // remain in flight while the oldest 4 (stage ki) have landed -> buffer
    // CUR is ready after the barrier. The lgkmcnt(0)+barrier BEFORE the MFMA
    // cluster releases buf CUR for overwrite while MFMAs (register-only)
    // still execute, overlapping other waves' next stage issue.
#define KSTEP(CUR, NXT, KI)                                                     \
    do {                                                                        \
        int ki_ = (KI);                                                         \
        if (ki_ + 2 < KITERS) {                                                 \
            stage(NXT, ki_ + 2);                                                \
            asm volatile("s_waitcnt vmcnt(8)\ns_barrier" ::: "memory");         \
        } else if (ki_ + 2 == KITERS) {                                         \
            asm volatile("s_waitcnt vmcnt(4)\ns_barrier" ::: "memory");         \
        } else {                                                                \
            asm volatile("s_waitcnt vmcnt(0)\ns_barrier" ::: "memory");         \
        }                                                                       \
        bf16x8 af[4], bfr[4];                                                   \
        _Pragma("unroll")                                                       \
        for (int mt = 0; mt < 4; mt++)                                          \
            af[mt] = *(const bf16x8*)&As[CUR][(wave_m + mt * 16 + lm) * 32 + sw]; \
        _Pragma("unroll")                                                       \
        for (int nt = 0; nt < 4; nt++)                                          \
            bfr[nt] = *(const bf16x8*)&Bs[CUR][(wave_n + nt * 16 + lm) * 32 + sw]; \
        asm volatile("s_waitcnt lgkmcnt(0)\ns_barrier" ::: "memory");           \
        _Pragma("unroll")                                                       \
        for (int mt = 0; mt < 4; mt++)                                          \
            _Pragma("unroll")                                                   \
            for (int nt = 0; nt < 4; nt++)                                      \
                acc[mt][nt] = __builtin_amdgcn_mfma_f32_16x16x32_bf16(          \
                    af[mt], bfr[nt], acc[mt][nt], 0, 0, 0);                     \
    } while (0)

    for (int kb = 0; kb < KITERS; kb += 3) {
        KSTEP(0, 2, kb);
        if (kb + 1 < KITERS) KSTEP(1, 0, kb + 1);
        if (kb + 2 < KITERS) KSTEP(2, 1, kb + 2);
    }
#undef KSTEP

    // C/D layout: col = lane&15, row = (lane>>4)*4 + reg  [m89/m91-verified]
    if (MODE == 0) {
        ushort_t* hp = (ushort_t*)Cout + (size_t)wi * 128 * HH;
#pragma unroll
        for (int mt = 0; mt < 4; mt++) {
#pragma unroll
            for (int r = 0; r < 4; r++) {
                int row = wave_m + mt * 16 + quad * 4 + r;
#pragma unroll
                for (int nt = 0; nt < 4; nt++) {
                    int col = col0 + wave_n + nt * 16 + lm;
                    hp[(size_t)row * HH + col] = f2bf(fmaxf(acc[mt][nt][r], 0.f));
                }
            }
        }
    } else {
        float* outp = (float*)Cout;
#pragma unroll
        for (int mt = 0; mt < 4; mt++) {
#pragma unroll
            for (int r = 0; r < 4; r++) {
                int row = wave_m + mt * 16 + quad * 4 + r;
                int slot = e * MM + ytile * 128 + row;
                int tok = s2t[slot];
                if (tok < 0) continue;
                float g = s2g[slot];
#pragma unroll
                for (int nt = 0; nt < 4; nt++) {
                    int col = col0 + wave_n + nt * 16 + lm;
                    atomicAdd(outp + (size_t)tok * DD + col, g * acc[mt][nt][r]);
                }
            }
        }
    }
}

// ---------------------------------------------------------------------------
// Workspace layout (bytes), total ~126.2 MB (< 151.2 MB proven):
//   0         e1 32768 | 32768 e2 | 65536 g1 | 98304 g2
//   131072    used (pad 1024)
//   132096    meta (5136 ints = 20544 B, pad to 20608)
//   152704    s2t  131072
//   283776    s2g  131072
//   414848    xbf  bf16 [8192][512]            =  8,388,608
//   8803456   wt   bf16 (w1t, then w2t)        = 33,554,432
//   42357888  hid  bf16 [160 strips][128][2048]= 83,886,080
// ---------------------------------------------------------------------------
extern "C" void kernel_launch(void* const* d_in, const int* in_sizes, int n_in,
                              void* d_out, int out_size, void* d_ws, size_t ws_size,
                              hipStream_t stream) {
    const float* x  = (const float*)d_in[0];
    const float* wg = (const float*)d_in[1];
    const float* w1 = (const float*)d_in[2];
    const float* w2 = (const float*)d_in[3];
    float* out = (float*)d_out;

    char* ws = (char*)d_ws;
    int*      e1   = (int*)(ws);
    int*      e2   = (int*)(ws + 32768);
    float*    g1   = (float*)(ws + 65536);
    float*    g2   = (float*)(ws + 98304);
    int*      used = (int*)(ws + 131072);
    int*      meta = (int*)(ws + 132096);
    int*      s2t  = (int*)(ws + 152704);
    float*    s2g  = (float*)(ws + 283776);
    ushort_t* xbf  = (ushort_t*)(ws + 414848);
    ushort_t* wt   = (ushort_t*)(ws + 8803456);
    ushort_t* hid  = (ushort_t*)(ws + 42357888);

    hipMemsetAsync(out, 0, (size_t)NTOK * DD * sizeof(float), stream);

    gating_kernel<<<NTOK / 4, 256, 0, stream>>>(x, wg, e1, e2, g1, g2, xbf);
    scan_kernel<<<BB * EE, 256, 0, stream>>>(e1, e2, g1, g2, s2t, s2g, used);
    schedule_kernel<<<1, 64, 0, stream>>>(used, meta);

    // GEMM1: gather(xbf) @ w1t -> relu -> hid (compact strips), XCD-pinned
    transpose_bf16<<<dim3(HH / 64, DD / 64, EE), 256, 0, stream>>>(w1, wt, DD, HH);
    gemm_mfma<0><<<dim3(8, 512), 256, 0, stream>>>(xbf, wt, hid, meta, s2t, s2g);

    // GEMM2: hid @ w2t -> gate-weighted scatter-add into out, XCD-pinned
    transpose_bf16<<<dim3(DD / 64, HH / 64, EE), 256, 0, stream>>>(w2, wt, HH, DD);
    gemm_mfma<1><<<dim3(8, 128), 256, 0, stream>>>(hid, wt, out, meta, s2t, s2g);
}

// Round 9
// 342.019 us; speedup vs baseline: 1.2268x; 1.0255x over previous
//
#include <hip/hip_runtime.h>

// Problem constants (from reference setup_inputs)
#define BB 2
#define NN 4096
#define DD 512
#define EE 16
#define HH 2048
#define CAP 1024            // capacity = int((4096*2)*2.0/16) = 1024
#define NTOK (BB*NN)        // 8192
#define MM (BB*CAP)         // 2048 = per-expert logical M
#define MAXSTRIP 160        // worst-case total 128-row strips (<=158)

typedef unsigned short ushort_t;
typedef __attribute__((ext_vector_type(8))) short bf16x8;   // 8 bf16 = 4 VGPRs
typedef __attribute__((ext_vector_type(4))) float floatx4;  // MFMA accumulator

// round-to-nearest-even f32 -> bf16 bit pattern
__device__ __forceinline__ ushort_t f2bf(float f) {
    union { float f; unsigned u; } v; v.f = f;
    unsigned r = v.u + 0x7fffu + ((v.u >> 16) & 1u);
    return (ushort_t)(r >> 16);
}

// async global->LDS, 16B per lane (global_load_lds_dwordx4).
__device__ __forceinline__ void cp16(const void* g, void* l) {
    __builtin_amdgcn_global_load_lds(
        (const __attribute__((address_space(1))) void*)g,
        (__attribute__((address_space(3))) void*)l, 16, 0, 0);
}

// ---------------------------------------------------------------------------
// Kernel 0: transpose gating weights wg [512][16] -> wgT [16][512] (f32).
// 8192 elements, one block. Makes gating's weight reads coalescible.
// ---------------------------------------------------------------------------
__global__ void transpose_wg(const float* __restrict__ wg, float* __restrict__ wgT) {
    for (int idx = threadIdx.x; idx < DD * EE; idx += 256) {
        int d = idx >> 4, e = idx & 15;
        wgT[e * DD + d] = wg[d * EE + e];
    }
}

// ---------------------------------------------------------------------------
// Kernel 1: gating (f32-exact selection) + fused bf16 conversion of x.
// Reads wgT [16][512]: per expert, two float4 per lane -> fully coalesced,
// L1-resident. fmaf chain order identical to the previous version
// (acc[e] over j ascending) -> bit-identical selection and gates.
// ---------------------------------------------------------------------------
__launch_bounds__(256)
__global__ void gating_kernel(const float* __restrict__ x,
                              const float* __restrict__ wgT,
                              int* __restrict__ e1, int* __restrict__ e2,
                              float* __restrict__ g1, float* __restrict__ g2,
                              ushort_t* __restrict__ xbf) {
    int wave = threadIdx.x >> 6;
    int lane = threadIdx.x & 63;
    int t = blockIdx.x * 4 + wave;
    const float* xp = x + (size_t)t * DD;

    float4 xa = ((const float4*)xp)[lane * 2];
    float4 xb = ((const float4*)xp)[lane * 2 + 1];
    float xs[8] = {xa.x, xa.y, xa.z, xa.w, xb.x, xb.y, xb.z, xb.w};

    ushort4 h0, h1;
    h0.x = f2bf(xs[0]); h0.y = f2bf(xs[1]); h0.z = f2bf(xs[2]); h0.w = f2bf(xs[3]);
    h1.x = f2bf(xs[4]); h1.y = f2bf(xs[5]); h1.z = f2bf(xs[6]); h1.w = f2bf(xs[7]);
    ushort4* xo = (ushort4*)(xbf + (size_t)t * DD);
    xo[lane * 2] = h0; xo[lane * 2 + 1] = h1;

    int d0 = lane * 8;
    float acc[EE];
#pragma unroll
    for (int e = 0; e < EE; e++) {
        const float4* wr = (const float4*)(wgT + e * DD + d0);
        float4 wa = wr[0], wb = wr[1];
        float a = 0.f;
        a = fmaf(xs[0], wa.x, a); a = fmaf(xs[1], wa.y, a);
        a = fmaf(xs[2], wa.z, a); a = fmaf(xs[3], wa.w, a);
        a = fmaf(xs[4], wb.x, a); a = fmaf(xs[5], wb.y, a);
        a = fmaf(xs[6], wb.z, a); a = fmaf(xs[7], wb.w, a);
        acc[e] = a;
    }
#pragma unroll
    for (int off = 32; off > 0; off >>= 1) {
#pragma unroll
        for (int e = 0; e < EE; e++) acc[e] += __shfl_xor(acc[e], off, 64);
    }
    if (lane == 0) {
        float m = acc[0];
#pragma unroll
        for (int e = 1; e < EE; e++) m = fmaxf(m, acc[e]);
        float p[EE]; float s = 0.f;
#pragma unroll
        for (int e = 0; e < EE; e++) { p[e] = __expf(acc[e] - m); s += p[e]; }
        float inv = 1.f / s;
#pragma unroll
        for (int e = 0; e < EE; e++) p[e] *= inv;
        int i1 = 0; float v1 = p[0];
#pragma unroll
        for (int e = 1; e < EE; e++) if (p[e] > v1) { v1 = p[e]; i1 = e; }
        int i2 = (i1 == 0) ? 1 : 0; float v2 = p[i2];
#pragma unroll
        for (int e = 0; e < EE; e++)
            if (e != i1 && p[e] > v2) { v2 = p[e]; i2 = e; }
        float denom = v1 + v2 + 1e-9f;
        e1[t] = i1; e2[t] = i2;
        g1[t] = v1 / denom; g2[t] = v2 / denom;
    }
}

// ---------------------------------------------------------------------------
// Kernel 2: per-(b,e) exclusive scan -> slot assignment with capacity drop.
// Wave-shuffle scan (1 barrier). Order-preserving: prefix by tid then j-order
// within thread == token order. Writes s2t (token or -1 for ALL CAP slots),
// s2g, used[e][b].
// ---------------------------------------------------------------------------
__launch_bounds__(256)
__global__ void scan_kernel(const int* __restrict__ e1, const int* __restrict__ e2,
                            const float* __restrict__ g1, const float* __restrict__ g2,
                            int* __restrict__ s2t, float* __restrict__ s2g,
                            int* __restrict__ used) {
    int b = blockIdx.x / EE;
    int e = blockIdx.x % EE;
    int tid = threadIdx.x;
    int lane = tid & 63;
    int w = tid >> 6;
    const int base = b * NN;
    int n0 = tid * 16;

    unsigned m1 = 0, m2 = 0;
    int c1 = 0, c2 = 0;
#pragma unroll
    for (int j = 0; j < 16; j++) {
        int n = n0 + j;
        if (e1[base + n] == e) { m1 |= 1u << j; c1++; }
        if (e2[base + n] == e) { m2 |= 1u << j; c2++; }
    }
    // in-wave inclusive scans (no barriers)
    int i1 = c1, i2 = c2;
#pragma unroll
    for (int off = 1; off < 64; off <<= 1) {
        int t1 = __shfl_up(i1, off, 64);
        int t2 = __shfl_up(i2, off, 64);
        if (lane >= off) { i1 += t1; i2 += t2; }
    }
    __shared__ int ws1[4], ws2[4];
    if (lane == 63) { ws1[w] = i1; ws2[w] = i2; }
    __syncthreads();
    int p1 = 0, p2 = 0, total1 = 0, total2 = 0;
#pragma unroll
    for (int k = 0; k < 4; k++) {
        int v1 = ws1[k], v2 = ws2[k];
        if (k < w) { p1 += v1; p2 += v2; }
        total1 += v1; total2 += v2;
    }
    int kept1 = min(total1, CAP);
    int ex1 = p1 + i1 - c1;                 // block-exclusive prefix, list 1
    int ex2 = p2 + i2 - c2 + kept1;         // list 2 starts after kept list-1
    const int sbase = (e * BB + b) * CAP;
#pragma unroll
    for (int j = 0; j < 16; j++) {
        int n = n0 + j;
        if (m1 & (1u << j)) {
            if (ex1 < CAP) { s2t[sbase + ex1] = base + n; s2g[sbase + ex1] = g1[base + n]; }
            ex1++;
        }
        if (m2 & (1u << j)) {
            if (ex2 < CAP) { s2t[sbase + ex2] = base + n; s2g[sbase + ex2] = g2[base + n]; }
            ex2++;
        }
    }
    int kept2 = min(total2, max(0, CAP - kept1));
    int u = kept1 + kept2;
    if (tid == 0) used[e * BB + b] = u;
    // emits cover [0, u); fill the rest (disjoint -> no extra barrier needed)
    for (int i = u + tid; i < CAP; i += 256) s2t[sbase + i] = -1;
}

// ---------------------------------------------------------------------------
// Kernel 3: build XCD-pinned job schedules. Expert e is pinned to XCD e&7
// (two experts per XCD). With grid (8, slots), linear block id = x + 8*y, and
// round-robin dispatch puts all blocks with blockIdx.x == x on XCD x, so each
// XCD's L2 only holds its 2 experts' weight slabs + A rows.
// meta layout (ints): [0..7] count1/xcd, [8..15] count2/xcd,
//                     [16..4111] sched1 (8 x 512), [4112..5135] sched2 (8 x 128)
// job = (e<<17) | (wi<<9) | (ytile<<5) | col   (wi = global compact strip id)
// ---------------------------------------------------------------------------
__global__ void schedule_kernel(const int* __restrict__ used, int* __restrict__ meta) {
    __shared__ int ns[32], pre[32];
    int i = threadIdx.x;
    if (i < 32) {
        int e = i >> 1, b = i & 1;
        ns[i] = (used[e * BB + b] + 127) >> 7;
    }
    __syncthreads();
    if (i == 0) {
        int acc = 0;
        for (int j = 0; j < 32; j++) { pre[j] = acc; acc += ns[j]; }
    }
    __syncthreads();
    if (i < 16) {
        int e = i;
        int xcd = e & 7;
        int mine  = ns[2 * e] + ns[2 * e + 1];
        int po    = (e < 8) ? (e + 8) : (e - 8);
        int other = ns[2 * po] + ns[2 * po + 1];
        if (e < 8) {
            meta[xcd]     = (mine + other) * 16;   // GEMM1 jobs on this XCD
            meta[8 + xcd] = (mine + other) * 4;    // GEMM2 jobs on this XCD
        }
        int off = (e < 8) ? 0 : other;             // partner's jobs come first
        int* sc1 = meta + 16 + xcd * 512 + off * 16;
        int j = 0;
        for (int col = 0; col < 16; col++)
            for (int bb = 0; bb < 2; bb++)
                for (int s = 0; s < ns[2 * e + bb]; s++) {
                    int wi = pre[2 * e + bb] + s;
                    sc1[j++] = (e << 17) | (wi << 9) | ((bb * 8 + s) << 5) | col;
                }
        int* sc2 = meta + 16 + 4096 + xcd * 128 + off * 4;
        j = 0;
        for (int col = 0; col < 4; col++)
            for (int bb = 0; bb < 2; bb++)
                for (int s = 0; s < ns[2 * e + bb]; s++) {
                    int wi = pre[2 * e + bb] + s;
                    sc2[j++] = (e << 17) | (wi << 9) | ((bb * 8 + s) << 5) | col;
                }
    }
}

// ---------------------------------------------------------------------------
// Kernel 4: per-expert transpose + bf16: in f32 [E][R][C] -> out bf16 [E][C][R].
// 64x64 tiles, float4 loads (256B/16-lane group), LDS [64][65] (2-way bank
// aliasing = free), ushort4 stores (128B/16-lane group). Grid (C/64, R/64, E).
// ---------------------------------------------------------------------------
__launch_bounds__(256)
__global__ void transpose_bf16(const float* __restrict__ in,
                               ushort_t* __restrict__ outp, int R, int C) {
    __shared__ float tile[64][65];
    const float* slab = in + (size_t)blockIdx.z * R * C;
    ushort_t* oslab = outp + (size_t)blockIdx.z * R * C;
    int c0 = blockIdx.x * 64, r0 = blockIdx.y * 64;
    int tid = threadIdx.x;
    int rr = tid >> 4;          // 0..15
    int cc = tid & 15;          // 0..15
#pragma unroll
    for (int j = 0; j < 4; j++) {
        int row = rr + j * 16;
        float4 v = *(const float4*)(slab + (size_t)(r0 + row) * C + c0 + cc * 4);
        tile[row][cc * 4 + 0] = v.x;
        tile[row][cc * 4 + 1] = v.y;
        tile[row][cc * 4 + 2] = v.z;
        tile[row][cc * 4 + 3] = v.w;
    }
    __syncthreads();
#pragma unroll
    for (int j = 0; j < 4; j++) {
        int trow = rr + j * 16;              // = original col within tile
        ushort4 h;
        h.x = f2bf(tile[cc * 4 + 0][trow]);
        h.y = f2bf(tile[cc * 4 + 1][trow]);
        h.z = f2bf(tile[cc * 4 + 2][trow]);
        h.w = f2bf(tile[cc * 4 + 3][trow]);
        *(ushort4*)(oslab + (size_t)(c0 + trow) * R + r0 + cc * 4) = h;
    }
}

// ---------------------------------------------------------------------------
// Kernel 5: bf16 MFMA GEMM, 128x128 tile, BK=32, XCD-pinned job schedule,
// 3-stage software pipeline (prefetch distance 2, counted vmcnt(8) never
// drained in steady state), XOR-swizzled staging (0 bank conflicts).
// Read-complete barrier placed BEFORE the MFMA cluster so MFMAs overlap the
// next iteration's stage issue in other waves.
//   MODE 0 (GEMM1): K=512,  A gathered from xbf via s2t, relu -> hid[strip].
//   MODE 1 (GEMM2): K=2048, A = hid[strip], epilogue gate*acc atomicAdd -> out.
// ---------------------------------------------------------------------------
template <int MODE>
__launch_bounds__(256)
__global__ void gemm_mfma(const ushort_t* __restrict__ Abase,
                          const ushort_t* __restrict__ Bt,
                          void* __restrict__ Cout,
                          const int* __restrict__ meta,
                          const int* __restrict__ s2t,
                          const float* __restrict__ s2g) {
    constexpr int K = (MODE == 0) ? DD : HH;
    constexpr int KITERS = K / 32;

    int xcd = blockIdx.x;
    if ((int)blockIdx.y >= meta[(MODE == 0 ? 0 : 8) + xcd]) return;
    int job = meta[16 + (MODE == 0 ? 0 : 4096) + xcd * (MODE == 0 ? 512 : 128) + blockIdx.y];
    int col0  = (job & 31) * 128;
    int ytile = (job >> 5) & 15;
    int wi    = (job >> 9) & 255;
    int e     = job >> 17;

    // 3-stage pipeline: 3 x (8KB A + 8KB B) = 48KB -> 3 blocks/CU
    __shared__ ushort_t As[3][128 * 32];
    __shared__ ushort_t Bs[3][128 * 32];

    int tid = threadIdx.x;
    int lane = tid & 63;
    int wid = tid >> 6;
    int wave_m = (wid & 1) << 6;
    int wave_n = (wid >> 1) << 6;
    int lm = lane & 15;
    int quad = lane >> 4;
    // fragment-read swizzle: global chunk (r, c) stored at LDS col c ^ ((r>>1)&3)
    int sw = (quad ^ ((lm >> 1) & 3)) * 8;

    // per-thread global chunk base pointers (k = 0)
    const ushort_t* ga[2];
    const ushort_t* gb[2];
#pragma unroll
    for (int it = 0; it < 2; it++) {
        int idx = it * 256 + tid;
        int r = idx >> 2;
        int cg = (idx & 3) ^ ((r >> 1) & 3);
        if (MODE == 0) {
            int tok = s2t[e * MM + ytile * 128 + r];
            if (tok < 0) tok = 0;   // dummy valid row; masked at epilogue
            ga[it] = Abase + (size_t)tok * DD + cg * 8;
        } else {
            ga[it] = Abase + (size_t)(wi * 128 + r) * HH + cg * 8;
        }
        gb[it] = Bt + (size_t)e * HH * DD + (size_t)(col0 + r) * K + cg * 8;
    }

    auto stage = [&](int buf, int ki) {
#pragma unroll
        for (int it = 0; it < 2; it++)
            cp16(ga[it] + ki * 32, &As[buf][(it * 256 + tid) * 8]);
#pragma unroll
        for (int it = 0; it < 2; it++)
            cp16(gb[it] + ki * 32, &Bs[buf][(it * 256 + tid) * 8]);
    };

    floatx4 acc[4][4];
#pragma unroll
    for (int i = 0; i < 4; i++)
#pragma unroll
        for (int j = 0; j < 4; j++)
            acc[i][j] = (floatx4)(0.f);

    // Prologue: two tiles in flight.
    stage(0, 0);
    stage(1, 1);

    // One K-step; CUR/NXT are literal constants at every expansion so LDS
    // bases are compile-time. vmcnt(8): stages ki+1, ki+2 (4 loads each)
    // remain in flight while the oldest 4 (stage ki) have landed -> buffer
    // CUR is ready after the barrier. The lgkmcnt(0)+barrier BEFORE the MFMA
    // cluster releases buf CUR for overwrite while MFMAs (register-only)
    // still execute, overlapping other waves' next stage issue.
#define KSTEP(CUR, NXT, KI)                                                     \
    do {                                                                        \
        int ki_ = (KI);                                                         \
        if (ki_ + 2 < KITERS) {                                                 \
            stage(NXT, ki_ + 2);                                                \
            asm volatile("s_waitcnt vmcnt(8)\ns_barrier" ::: "memory");         \
        } else if (ki_ + 2 == KITERS) {                                         \
            asm volatile("s_waitcnt vmcnt(4)\ns_barrier" ::: "memory");         \
        } else {                                                                \
            asm volatile("s_waitcnt vmcnt(0)\ns_barrier" ::: "memory");         \
        }                                                                       \
        bf16x8 af[4], bfr[4];                                                   \
        _Pragma("unroll")                                                       \
        for (int mt = 0; mt < 4; mt++)                                          \
            af[mt] = *(const bf16x8*)&As[CUR][(wave_m + mt * 16 + lm) * 32 + sw]; \
        _Pragma("unroll")                                                       \
        for (int nt = 0; nt < 4; nt++)                                          \
            bfr[nt] = *(const bf16x8*)&Bs[CUR][(wave_n + nt * 16 + lm) * 32 + sw]; \
        asm volatile("s_waitcnt lgkmcnt(0)\ns_barrier" ::: "memory");           \
        _Pragma("unroll")                                                       \
        for (int mt = 0; mt < 4; mt++)                                          \
            _Pragma("unroll")                                                   \
            for (int nt = 0; nt < 4; nt++)                                      \
                acc[mt][nt] = __builtin_amdgcn_mfma_f32_16x16x32_bf16(          \
                    af[mt], bfr[nt], acc[mt][nt], 0, 0, 0);                     \
    } while (0)

    for (int kb = 0; kb < KITERS; kb += 3) {
        KSTEP(0, 2, kb);
        if (kb + 1 < KITERS) KSTEP(1, 0, kb + 1);
        if (kb + 2 < KITERS) KSTEP(2, 1, kb + 2);
    }
#undef KSTEP

    // C/D layout: col = lane&15, row = (lane>>4)*4 + reg  [m89/m91-verified]
    if (MODE == 0) {
        ushort_t* hp = (ushort_t*)Cout + (size_t)wi * 128 * HH;
#pragma unroll
        for (int mt = 0; mt < 4; mt++) {
#pragma unroll
            for (int r = 0; r < 4; r++) {
                int row = wave_m + mt * 16 + quad * 4 + r;
#pragma unroll
                for (int nt = 0; nt < 4; nt++) {
                    int col = col0 + wave_n + nt * 16 + lm;
                    hp[(size_t)row * HH + col] = f2bf(fmaxf(acc[mt][nt][r], 0.f));
                }
            }
        }
    } else {
        float* outp = (float*)Cout;
#pragma unroll
        for (int mt = 0; mt < 4; mt++) {
#pragma unroll
            for (int r = 0; r < 4; r++) {
                int row = wave_m + mt * 16 + quad * 4 + r;
                int slot = e * MM + ytile * 128 + row;
                int tok = s2t[slot];
                if (tok < 0) continue;
                float g = s2g[slot];
#pragma unroll
                for (int nt = 0; nt < 4; nt++) {
                    int col = col0 + wave_n + nt * 16 + lm;
                    atomicAdd(outp + (size_t)tok * DD + col, g * acc[mt][nt][r]);
                }
            }
        }
    }
}

// ---------------------------------------------------------------------------
// Workspace layout (bytes), total ~126.3 MB (< 151.2 MB proven):
//   0         e1 32768 | 32768 e2 | 65536 g1 | 98304 g2
//   131072    used (pad 1024)
//   132096    meta (5136 ints = 20544 B, pad to 20608)
//   152704    s2t  131072
//   283776    s2g  131072
//   414848    xbf  bf16 [8192][512]            =  8,388,608
//   8803456   wt   bf16 (w1t, then w2t)        = 33,554,432
//   42357888  hid  bf16 [160 strips][128][2048]= 83,886,080
//   126243968 wgT  f32 [16][512]               =      32,768
// ---------------------------------------------------------------------------
extern "C" void kernel_launch(void* const* d_in, const int* in_sizes, int n_in,
                              void* d_out, int out_size, void* d_ws, size_t ws_size,
                              hipStream_t stream) {
    const float* x  = (const float*)d_in[0];
    const float* wg = (const float*)d_in[1];
    const float* w1 = (const float*)d_in[2];
    const float* w2 = (const float*)d_in[3];
    float* out = (float*)d_out;

    char* ws = (char*)d_ws;
    int*      e1   = (int*)(ws);
    int*      e2   = (int*)(ws + 32768);
    float*    g1   = (float*)(ws + 65536);
    float*    g2   = (float*)(ws + 98304);
    int*      used = (int*)(ws + 131072);
    int*      meta = (int*)(ws + 132096);
    int*      s2t  = (int*)(ws + 152704);
    float*    s2g  = (float*)(ws + 283776);
    ushort_t* xbf  = (ushort_t*)(ws + 414848);
    ushort_t* wt   = (ushort_t*)(ws + 8803456);
    ushort_t* hid  = (ushort_t*)(ws + 42357888);
    float*    wgT  = (float*)(ws + 126243968);

    hipMemsetAsync(out, 0, (size_t)NTOK * DD * sizeof(float), stream);

    transpose_wg<<<1, 256, 0, stream>>>(wg, wgT);
    gating_kernel<<<NTOK / 4, 256, 0, stream>>>(x, wgT, e1, e2, g1, g2, xbf);
    scan_kernel<<<BB * EE, 256, 0, stream>>>(e1, e2, g1, g2, s2t, s2g, used);
    schedule_kernel<<<1, 64, 0, stream>>>(used, meta);

    // GEMM1: gather(xbf) @ w1t -> relu -> hid (compact strips), XCD-pinned
    transpose_bf16<<<dim3(HH / 64, DD / 64, EE), 256, 0, stream>>>(w1, wt, DD, HH);
    gemm_mfma<0><<<dim3(8, 512), 256, 0, stream>>>(xbf, wt, hid, meta, s2t, s2g);

    // GEMM2: hid @ w2t -> gate-weighted scatter-add into out, XCD-pinned
    transpose_bf16<<<dim3(DD / 64, HH / 64, EE), 256, 0, stream>>>(w2, wt, HH, DD);
    gemm_mfma<1><<<dim3(8, 128), 256, 0, stream>>>(hid, wt, out, meta, s2t, s2g);
}

// Round 10
// 321.243 us; speedup vs baseline: 1.3061x; 1.0647x over previous
//
#include <hip/hip_runtime.h>

// Problem constants (from reference setup_inputs)
#define BB 2
#define NN 4096
#define DD 512
#define EE 16
#define HH 2048
#define CAP 1024            // capacity = int((4096*2)*2.0/16) = 1024
#define NTOK (BB*NN)        // 8192
#define MM (BB*CAP)         // 2048 = per-expert logical M
#define MAXSTRIP 160        // worst-case total 128-row strips (<=158)

typedef unsigned short ushort_t;
typedef __attribute__((ext_vector_type(8))) short bf16x8;   // 8 bf16 = 4 VGPRs
typedef __attribute__((ext_vector_type(4))) float floatx4;  // MFMA accumulator

// round-to-nearest-even f32 -> bf16 bit pattern
__device__ __forceinline__ ushort_t f2bf(float f) {
    union { float f; unsigned u; } v; v.f = f;
    unsigned r = v.u + 0x7fffu + ((v.u >> 16) & 1u);
    return (ushort_t)(r >> 16);
}

// async global->LDS, 16B per lane (global_load_lds_dwordx4).
__device__ __forceinline__ void cp16(const void* g, void* l) {
    __builtin_amdgcn_global_load_lds(
        (const __attribute__((address_space(1))) void*)g,
        (__attribute__((address_space(3))) void*)l, 16, 0, 0);
}

// ---------------------------------------------------------------------------
// Kernel 0 (prep): fused {out zeroing, wg transpose, w1 transpose+bf16}.
// Grid (HH/64, DD/64, EE) = 4096 blocks x 256 thr. Each block transposes one
// 64x64 w1 tile (verified vectorized pattern), zeroes its 1024-float share of
// out (4096*256 float4 == NTOK*DD exactly), and block 0 writes wgT.
// ---------------------------------------------------------------------------
__launch_bounds__(256)
__global__ void prep_kernel(const float* __restrict__ w1,
                            ushort_t* __restrict__ w1t,
                            const float* __restrict__ wg,
                            float* __restrict__ wgT,
                            float* __restrict__ out) {
    __shared__ float tile[64][65];
    const int R = DD, C = HH;
    const float* slab = w1 + (size_t)blockIdx.z * R * C;
    ushort_t* oslab = w1t + (size_t)blockIdx.z * R * C;
    int c0 = blockIdx.x * 64, r0 = blockIdx.y * 64;
    int tid = threadIdx.x;
    int rr = tid >> 4;          // 0..15
    int cc = tid & 15;          // 0..15
#pragma unroll
    for (int j = 0; j < 4; j++) {
        int row = rr + j * 16;
        float4 v = *(const float4*)(slab + (size_t)(r0 + row) * C + c0 + cc * 4);
        tile[row][cc * 4 + 0] = v.x;
        tile[row][cc * 4 + 1] = v.y;
        tile[row][cc * 4 + 2] = v.z;
        tile[row][cc * 4 + 3] = v.w;
    }
    // zero-share of out (independent of the transpose data; overlaps LDS fill)
    int bid = blockIdx.x + (C / 64) * (blockIdx.y + (R / 64) * blockIdx.z);
    ((float4*)out)[bid * 256 + tid] = make_float4(0.f, 0.f, 0.f, 0.f);
    if (bid == 0) {   // block-uniform branch (before barrier: all threads enter)
        for (int idx = tid; idx < DD * EE; idx += 256) {
            int d = idx >> 4, ee = idx & 15;
            wgT[ee * DD + d] = wg[d * EE + ee];
        }
    }
    __syncthreads();
#pragma unroll
    for (int j = 0; j < 4; j++) {
        int trow = rr + j * 16;              // = original col within tile
        ushort4 h;
        h.x = f2bf(tile[cc * 4 + 0][trow]);
        h.y = f2bf(tile[cc * 4 + 1][trow]);
        h.z = f2bf(tile[cc * 4 + 2][trow]);
        h.w = f2bf(tile[cc * 4 + 3][trow]);
        *(ushort4*)(oslab + (size_t)(c0 + trow) * R + r0 + cc * 4) = h;
    }
}

// ---------------------------------------------------------------------------
// Kernel 1: gating (f32-exact selection) + fused bf16 conversion of x.
// Reads wgT [16][512]: per expert, two float4 per lane -> fully coalesced.
// fmaf chain order identical to prior rounds -> bit-identical selection.
// ---------------------------------------------------------------------------
__launch_bounds__(256)
__global__ void gating_kernel(const float* __restrict__ x,
                              const float* __restrict__ wgT,
                              int* __restrict__ e1, int* __restrict__ e2,
                              float* __restrict__ g1, float* __restrict__ g2,
                              ushort_t* __restrict__ xbf) {
    int wave = threadIdx.x >> 6;
    int lane = threadIdx.x & 63;
    int t = blockIdx.x * 4 + wave;
    const float* xp = x + (size_t)t * DD;

    float4 xa = ((const float4*)xp)[lane * 2];
    float4 xb = ((const float4*)xp)[lane * 2 + 1];
    float xs[8] = {xa.x, xa.y, xa.z, xa.w, xb.x, xb.y, xb.z, xb.w};

    ushort4 h0, h1;
    h0.x = f2bf(xs[0]); h0.y = f2bf(xs[1]); h0.z = f2bf(xs[2]); h0.w = f2bf(xs[3]);
    h1.x = f2bf(xs[4]); h1.y = f2bf(xs[5]); h1.z = f2bf(xs[6]); h1.w = f2bf(xs[7]);
    ushort4* xo = (ushort4*)(xbf + (size_t)t * DD);
    xo[lane * 2] = h0; xo[lane * 2 + 1] = h1;

    int d0 = lane * 8;
    float acc[EE];
#pragma unroll
    for (int e = 0; e < EE; e++) {
        const float4* wr = (const float4*)(wgT + e * DD + d0);
        float4 wa = wr[0], wb = wr[1];
        float a = 0.f;
        a = fmaf(xs[0], wa.x, a); a = fmaf(xs[1], wa.y, a);
        a = fmaf(xs[2], wa.z, a); a = fmaf(xs[3], wa.w, a);
        a = fmaf(xs[4], wb.x, a); a = fmaf(xs[5], wb.y, a);
        a = fmaf(xs[6], wb.z, a); a = fmaf(xs[7], wb.w, a);
        acc[e] = a;
    }
#pragma unroll
    for (int off = 32; off > 0; off >>= 1) {
#pragma unroll
        for (int e = 0; e < EE; e++) acc[e] += __shfl_xor(acc[e], off, 64);
    }
    if (lane == 0) {
        float m = acc[0];
#pragma unroll
        for (int e = 1; e < EE; e++) m = fmaxf(m, acc[e]);
        float p[EE]; float s = 0.f;
#pragma unroll
        for (int e = 0; e < EE; e++) { p[e] = __expf(acc[e] - m); s += p[e]; }
        float inv = 1.f / s;
#pragma unroll
        for (int e = 0; e < EE; e++) p[e] *= inv;
        int i1 = 0; float v1 = p[0];
#pragma unroll
        for (int e = 1; e < EE; e++) if (p[e] > v1) { v1 = p[e]; i1 = e; }
        int i2 = (i1 == 0) ? 1 : 0; float v2 = p[i2];
#pragma unroll
        for (int e = 0; e < EE; e++)
            if (e != i1 && p[e] > v2) { v2 = p[e]; i2 = e; }
        float denom = v1 + v2 + 1e-9f;
        e1[t] = i1; e2[t] = i2;
        g1[t] = v1 / denom; g2[t] = v2 / denom;
    }
}

// ---------------------------------------------------------------------------
// Kernel 2: per-(b,e) exclusive scan -> slot assignment with capacity drop.
// Wave-shuffle scan (1 barrier). Order-preserving. Writes s2t (token or -1
// for ALL CAP slots), s2g, used[e][b].
// ---------------------------------------------------------------------------
__launch_bounds__(256)
__global__ void scan_kernel(const int* __restrict__ e1, const int* __restrict__ e2,
                            const float* __restrict__ g1, const float* __restrict__ g2,
                            int* __restrict__ s2t, float* __restrict__ s2g,
                            int* __restrict__ used) {
    int b = blockIdx.x / EE;
    int e = blockIdx.x % EE;
    int tid = threadIdx.x;
    int lane = tid & 63;
    int w = tid >> 6;
    const int base = b * NN;
    int n0 = tid * 16;

    unsigned m1 = 0, m2 = 0;
    int c1 = 0, c2 = 0;
#pragma unroll
    for (int j = 0; j < 16; j++) {
        int n = n0 + j;
        if (e1[base + n] == e) { m1 |= 1u << j; c1++; }
        if (e2[base + n] == e) { m2 |= 1u << j; c2++; }
    }
    // in-wave inclusive scans (no barriers)
    int i1 = c1, i2 = c2;
#pragma unroll
    for (int off = 1; off < 64; off <<= 1) {
        int t1 = __shfl_up(i1, off, 64);
        int t2 = __shfl_up(i2, off, 64);
        if (lane >= off) { i1 += t1; i2 += t2; }
    }
    __shared__ int ws1[4], ws2[4];
    if (lane == 63) { ws1[w] = i1; ws2[w] = i2; }
    __syncthreads();
    int p1 = 0, p2 = 0, total1 = 0, total2 = 0;
#pragma unroll
    for (int k = 0; k < 4; k++) {
        int v1 = ws1[k], v2 = ws2[k];
        if (k < w) { p1 += v1; p2 += v2; }
        total1 += v1; total2 += v2;
    }
    int kept1 = min(total1, CAP);
    int ex1 = p1 + i1 - c1;                 // block-exclusive prefix, list 1
    int ex2 = p2 + i2 - c2 + kept1;         // list 2 starts after kept list-1
    const int sbase = (e * BB + b) * CAP;
#pragma unroll
    for (int j = 0; j < 16; j++) {
        int n = n0 + j;
        if (m1 & (1u << j)) {
            if (ex1 < CAP) { s2t[sbase + ex1] = base + n; s2g[sbase + ex1] = g1[base + n]; }
            ex1++;
        }
        if (m2 & (1u << j)) {
            if (ex2 < CAP) { s2t[sbase + ex2] = base + n; s2g[sbase + ex2] = g2[base + n]; }
            ex2++;
        }
    }
    int kept2 = min(total2, max(0, CAP - kept1));
    int u = kept1 + kept2;
    if (tid == 0) used[e * BB + b] = u;
    // emits cover [0, u); fill the rest (disjoint -> no extra barrier needed)
    for (int i = u + tid; i < CAP; i += 256) s2t[sbase + i] = -1;
}

// ---------------------------------------------------------------------------
// Kernel 4: per-expert transpose + bf16: in f32 [E][R][C] -> out bf16 [E][C][R].
// 64x64 tiles, float4 loads, LDS [64][65], ushort4 stores. (Used for w2 only;
// w1's transpose is fused into prep_kernel.)
// ---------------------------------------------------------------------------
__launch_bounds__(256)
__global__ void transpose_bf16(const float* __restrict__ in,
                               ushort_t* __restrict__ outp, int R, int C) {
    __shared__ float tile[64][65];
    const float* slab = in + (size_t)blockIdx.z * R * C;
    ushort_t* oslab = outp + (size_t)blockIdx.z * R * C;
    int c0 = blockIdx.x * 64, r0 = blockIdx.y * 64;
    int tid = threadIdx.x;
    int rr = tid >> 4;          // 0..15
    int cc = tid & 15;          // 0..15
#pragma unroll
    for (int j = 0; j < 4; j++) {
        int row = rr + j * 16;
        float4 v = *(const float4*)(slab + (size_t)(r0 + row) * C + c0 + cc * 4);
        tile[row][cc * 4 + 0] = v.x;
        tile[row][cc * 4 + 1] = v.y;
        tile[row][cc * 4 + 2] = v.z;
        tile[row][cc * 4 + 3] = v.w;
    }
    __syncthreads();
#pragma unroll
    for (int j = 0; j < 4; j++) {
        int trow = rr + j * 16;              // = original col within tile
        ushort4 h;
        h.x = f2bf(tile[cc * 4 + 0][trow]);
        h.y = f2bf(tile[cc * 4 + 1][trow]);
        h.z = f2bf(tile[cc * 4 + 2][trow]);
        h.w = f2bf(tile[cc * 4 + 3][trow]);
        *(ushort4*)(oslab + (size_t)(c0 + trow) * R + r0 + cc * 4) = h;
    }
}

// ---------------------------------------------------------------------------
// Kernel 5: bf16 MFMA GEMM, 128x128 tile, BK=32, XCD-pinned, 3-stage pipeline
// (prefetch distance 2, counted vmcnt(8)), XOR-swizzled staging (0 conflicts).
// Job schedule decoded IN-KERNEL from used[] (replaces schedule_kernel+meta):
// replicates the exact enumeration {for col, for bb, for s} with expert
// blockIdx.x first, partner blockIdx.x+8 after.
//   MODE 0 (GEMM1): K=512,  A gathered from xbf via s2t, relu -> hid[strip].
//   MODE 1 (GEMM2): K=2048, A = hid[strip], epilogue gate*acc atomicAdd -> out.
// ---------------------------------------------------------------------------
template <int MODE>
__launch_bounds__(256)
__global__ void gemm_mfma(const ushort_t* __restrict__ Abase,
                          const ushort_t* __restrict__ Bt,
                          void* __restrict__ Cout,
                          const int* __restrict__ used,
                          const int* __restrict__ s2t,
                          const float* __restrict__ s2g) {
    constexpr int K = (MODE == 0) ? DD : HH;
    constexpr int KITERS = K / 32;
    constexpr int NCOL = (MODE == 0) ? 16 : 4;

    // --- in-kernel job decode from used[] ---
    __shared__ int s_ns[32];
    int tid = threadIdx.x;
    if (tid < 32) s_ns[tid] = (used[tid] + 127) >> 7;   // ns[i], i = e*2+b
    __syncthreads();
    int eA = blockIdx.x, eB = blockIdx.x + 8;
    int nA0 = s_ns[2 * eA], nA1 = s_ns[2 * eA + 1];
    int nB0 = s_ns[2 * eB], nB1 = s_ns[2 * eB + 1];
    int sA = nA0 + nA1, sB = nB0 + nB1;
    int y = (int)blockIdx.y;
    if (y >= NCOL * (sA + sB)) return;
    int preA = 0;
    for (int i = 0; i < 32; i++) preA += (i < 2 * eA) ? s_ns[i] : 0;
    int preB = preA;
    for (int i = 2 * eA; i < 2 * eB; i++) preB += s_ns[i];
    int e, jj, st, n0, pre0;
    if (y < NCOL * sA) { e = eA; jj = y;            st = sA; n0 = nA0; pre0 = preA; }
    else               { e = eB; jj = y - NCOL * sA; st = sB; n0 = nB0; pre0 = preB; }
    int col = jj / st;
    int rem = jj - col * st;
    int bb = (rem >= n0) ? 1 : 0;
    int s  = bb ? rem - n0 : rem;
    int ytile = bb * 8 + s;            // strip index within (e): b*8 + s
    int wi    = pre0 + bb * n0 + s;    // global compact strip id
    int col0  = col * 128;

    // 3-stage pipeline: 3 x (8KB A + 8KB B) = 48KB -> 3 blocks/CU
    __shared__ ushort_t As[3][128 * 32];
    __shared__ ushort_t Bs[3][128 * 32];

    int lane = tid & 63;
    int wid = tid >> 6;
    int wave_m = (wid & 1) << 6;
    int wave_n = (wid >> 1) << 6;
    int lm = lane & 15;
    int quad = lane >> 4;
    // fragment-read swizzle: global chunk (r, c) stored at LDS col c ^ ((r>>1)&3)
    int sw = (quad ^ ((lm >> 1) & 3)) * 8;

    // per-thread global chunk base pointers (k = 0)
    const ushort_t* ga[2];
    const ushort_t* gb[2];
#pragma unroll
    for (int it = 0; it < 2; it++) {
        int idx = it * 256 + tid;
        int r = idx >> 2;
        int cg = (idx & 3) ^ ((r >> 1) & 3);
        if (MODE == 0) {
            int tok = s2t[e * MM + ytile * 128 + r];
            if (tok < 0) tok = 0;   // dummy valid row; masked at epilogue
            ga[it] = Abase + (size_t)tok * DD + cg * 8;
        } else {
            ga[it] = Abase + (size_t)(wi * 128 + r) * HH + cg * 8;
        }
        gb[it] = Bt + (size_t)e * HH * DD + (size_t)(col0 + r) * K + cg * 8;
    }

    auto stage = [&](int buf, int ki) {
#pragma unroll
        for (int it = 0; it < 2; it++)
            cp16(ga[it] + ki * 32, &As[buf][(it * 256 + tid) * 8]);
#pragma unroll
        for (int it = 0; it < 2; it++)
            cp16(gb[it] + ki * 32, &Bs[buf][(it * 256 + tid) * 8]);
    };

    floatx4 acc[4][4];
#pragma unroll
    for (int i = 0; i < 4; i++)
#pragma unroll
        for (int j = 0; j < 4; j++)
            acc[i][j] = (floatx4)(0.f);

    // Prologue: two tiles in flight.
    stage(0, 0);
    stage(1, 1);

    // One K-step; CUR/NXT are literal constants at every expansion so LDS
    // bases are compile-time. vmcnt(8): stages ki+1, ki+2 (4 loads each)
    // remain in flight while the oldest 4 (stage ki) have landed -> buffer
    // CUR is ready after the barrier. The lgkmcnt(0)+barrier BEFORE the MFMA
    // cluster releases buf CUR for overwrite while MFMAs (register-only)
    // still execute, overlapping other waves' next stage issue.
#define KSTEP(CUR, NXT, KI)                                                     \
    do {                                                                        \
        int ki_ = (KI);                                                         \
        if (ki_ + 2 < KITERS) {                                                 \
            stage(NXT, ki_ + 2);                                                \
            asm volatile("s_waitcnt vmcnt(8)\ns_barrier" ::: "memory");         \
        } else if (ki_ + 2 == KITERS) {                                         \
            asm volatile("s_waitcnt vmcnt(4)\ns_barrier" ::: "memory");         \
        } else {                                                                \
            asm volatile("s_waitcnt vmcnt(0)\ns_barrier" ::: "memory");         \
        }                                                                       \
        bf16x8 af[4], bfr[4];                                                   \
        _Pragma("unroll")                                                       \
        for (int mt = 0; mt < 4; mt++)                                          \
            af[mt] = *(const bf16x8*)&As[CUR][(wave_m + mt * 16 + lm) * 32 + sw]; \
        _Pragma("unroll")                                                       \
        for (int nt = 0; nt < 4; nt++)                                          \
            bfr[nt] = *(const bf16x8*)&Bs[CUR][(wave_n + nt * 16 + lm) * 32 + sw]; \
        asm volatile("s_waitcnt lgkmcnt(0)\ns_barrier" ::: "memory");           \
        _Pragma("unroll")                                                       \
        for (int mt = 0; mt < 4; mt++)                                          \
            _Pragma("unroll")                                                   \
            for (int nt = 0; nt < 4; nt++)                                      \
                acc[mt][nt] = __builtin_amdgcn_mfma_f32_16x16x32_bf16(          \
                    af[mt], bfr[nt], acc[mt][nt], 0, 0, 0);                     \
    } while (0)

    for (int kb = 0; kb < KITERS; kb += 3) {
        KSTEP(0, 2, kb);
        if (kb + 1 < KITERS) KSTEP(1, 0, kb + 1);
        if (kb + 2 < KITERS) KSTEP(2, 1, kb + 2);
    }
#undef KSTEP

    // C/D layout: col = lane&15, row = (lane>>4)*4 + reg  [m89/m91-verified]
    if (MODE == 0) {
        ushort_t* hp = (ushort_t*)Cout + (size_t)wi * 128 * HH;
#pragma unroll
        for (int mt = 0; mt < 4; mt++) {
#pragma unroll
            for (int r = 0; r < 4; r++) {
                int row = wave_m + mt * 16 + quad * 4 + r;
#pragma unroll
                for (int nt = 0; nt < 4; nt++) {
                    int col2 = col0 + wave_n + nt * 16 + lm;
                    hp[(size_t)row * HH + col2] = f2bf(fmaxf(acc[mt][nt][r], 0.f));
                }
            }
        }
    } else {
        float* outp = (float*)Cout;
#pragma unroll
        for (int mt = 0; mt < 4; mt++) {
#pragma unroll
            for (int r = 0; r < 4; r++) {
                int row = wave_m + mt * 16 + quad * 4 + r;
                int slot = e * MM + ytile * 128 + row;
                int tok = s2t[slot];
                if (tok < 0) continue;
                float g = s2g[slot];
#pragma unroll
                for (int nt = 0; nt < 4; nt++) {
                    int col2 = col0 + wave_n + nt * 16 + lm;
                    atomicAdd(outp + (size_t)tok * DD + col2, g * acc[mt][nt][r]);
                }
            }
        }
    }
}

// ---------------------------------------------------------------------------
// Workspace layout (bytes), total ~126.3 MB (< 151.2 MB proven):
//   0         e1 32768 | 32768 e2 | 65536 g1 | 98304 g2
//   131072    used (pad 1024)
//   132096    (former meta region, unused)
//   152704    s2t  131072
//   283776    s2g  131072
//   414848    xbf  bf16 [8192][512]            =  8,388,608
//   8803456   wt   bf16 (w1t, then w2t)        = 33,554,432
//   42357888  hid  bf16 [160 strips][128][2048]= 83,886,080
//   126243968 wgT  f32 [16][512]               =      32,768
// ---------------------------------------------------------------------------
extern "C" void kernel_launch(void* const* d_in, const int* in_sizes, int n_in,
                              void* d_out, int out_size, void* d_ws, size_t ws_size,
                              hipStream_t stream) {
    const float* x  = (const float*)d_in[0];
    const float* wg = (const float*)d_in[1];
    const float* w1 = (const float*)d_in[2];
    const float* w2 = (const float*)d_in[3];
    float* out = (float*)d_out;

    char* ws = (char*)d_ws;
    int*      e1   = (int*)(ws);
    int*      e2   = (int*)(ws + 32768);
    float*    g1   = (float*)(ws + 65536);
    float*    g2   = (float*)(ws + 98304);
    int*      used = (int*)(ws + 131072);
    int*      s2t  = (int*)(ws + 152704);
    float*    s2g  = (float*)(ws + 283776);
    ushort_t* xbf  = (ushort_t*)(ws + 414848);
    ushort_t* wt   = (ushort_t*)(ws + 8803456);
    ushort_t* hid  = (ushort_t*)(ws + 42357888);
    float*    wgT  = (float*)(ws + 126243968);

    // prep: zero(out) + wgT + w1 -> w1t (one dispatch)
    prep_kernel<<<dim3(HH / 64, DD / 64, EE), 256, 0, stream>>>(w1, wt, wg, wgT, out);

    gating_kernel<<<NTOK / 4, 256, 0, stream>>>(x, wgT, e1, e2, g1, g2, xbf);
    scan_kernel<<<BB * EE, 256, 0, stream>>>(e1, e2, g1, g2, s2t, s2g, used);

    // GEMM1: gather(xbf) @ w1t -> relu -> hid (compact strips), XCD-pinned,
    // job decode in-kernel from used[]
    gemm_mfma<0><<<dim3(8, 512), 256, 0, stream>>>(xbf, wt, hid, used, s2t, s2g);

    // GEMM2: hid @ w2t -> gate-weighted scatter-add into out, XCD-pinned
    transpose_bf16<<<dim3(DD / 64, HH / 64, EE), 256, 0, stream>>>(w2, wt, HH, DD);
    gemm_mfma<1><<<dim3(8, 128), 256, 0, stream>>>(hid, wt, out, used, s2t, s2g);
}